// Round 12
// baseline (1531.565 us; speedup 1.0000x reference)
//
#include <hip/hip_runtime.h>
#include <hip/hip_bf16.h>
#include <math.h>

typedef unsigned short ushort_t;
typedef __attribute__((ext_vector_type(8))) short short8;
typedef __attribute__((ext_vector_type(4))) float f32x4;

#define B_ 64
#define TV_ 80
#define TD_ 19
#define H_ 512
#define VD_ 4096
#define NV_ 10000
#define G4_ 2048
#define HN_ 32768  // B_*H_

__device__ __forceinline__ float bf2f(ushort_t u) {
  unsigned int x = ((unsigned int)u) << 16;
  float f;
  __builtin_memcpy(&f, &x, 4);
  return f;
}
__device__ __forceinline__ ushort_t f2bf(float f) {
  unsigned int x;
  __builtin_memcpy(&x, &f, 4);
  x = (x + 0x7FFFu + ((x >> 16) & 1u)) >> 16;
  return (ushort_t)x;
}
__device__ __forceinline__ float sigmoidf_(float x) { return 1.0f / (1.0f + expf(-x)); }
__device__ __forceinline__ short8 zero8() {
  short8 z = {0, 0, 0, 0, 0, 0, 0, 0};
  return z;
}
// unpack packed (hi | lo<<16) uints into bf16 fragments via v_perm
__device__ __forceinline__ short8 unpack_hi(uint4 q0, uint4 q1) {
  union { unsigned int u[4]; short8 s; } r;
  r.u[0] = __builtin_amdgcn_perm(q0.y, q0.x, 0x05040100u);
  r.u[1] = __builtin_amdgcn_perm(q0.w, q0.z, 0x05040100u);
  r.u[2] = __builtin_amdgcn_perm(q1.y, q1.x, 0x05040100u);
  r.u[3] = __builtin_amdgcn_perm(q1.w, q1.z, 0x05040100u);
  return r.s;
}
__device__ __forceinline__ short8 unpack_lo(uint4 q0, uint4 q1) {
  union { unsigned int u[4]; short8 s; } r;
  r.u[0] = __builtin_amdgcn_perm(q0.y, q0.x, 0x07060302u);
  r.u[1] = __builtin_amdgcn_perm(q0.w, q0.z, 0x07060302u);
  r.u[2] = __builtin_amdgcn_perm(q1.y, q1.x, 0x07060302u);
  r.u[3] = __builtin_amdgcn_perm(q1.w, q1.z, 0x07060302u);
  return r.s;
}

// ---------------- fp32 -> bf16 convert (video) ----------------
__global__ __launch_bounds__(256) void cvt_f32_bf16(const float* __restrict__ in,
                                                    ushort_t* __restrict__ outp, int n4) {
  int i = blockIdx.x * 256 + threadIdx.x;
  if (i < n4) {
    float4 v = reinterpret_cast<const float4*>(in)[i];
    ushort4 r;
    r.x = f2bf(v.x); r.y = f2bf(v.y); r.z = f2bf(v.z); r.w = f2bf(v.w);
    reinterpret_cast<ushort4*>(outp)[i] = r;
  }
}

// ---------------- fused small-tensor prep: cvts + zero-fills (one dispatch) ----------
__device__ __forceinline__ void cvt_blk(const float* __restrict__ in,
                                        ushort_t* __restrict__ outp, int local, int tid) {
  int i = local * 256 + tid;
  float4 v = reinterpret_cast<const float4*>(in)[i];
  ushort4 r;
  r.x = f2bf(v.x); r.y = f2bf(v.y); r.z = f2bf(v.z); r.w = f2bf(v.w);
  reinterpret_cast<ushort4*>(outp)[i] = r;
}
// block ranges: [0,2048) vpw | [2048,3072) wih0 | [3072,4096) wih2 | [4096,4864) ainw
// [4864,5120) aoutw | [5120,10120) ow | [10120,12680) vpf | 12680 flags(4KB)
// [12681,12713) ringA slot0 | [12713,12745) ringB slot0
__global__ __launch_bounds__(256) void prep_small(
    const float* __restrict__ vpw, ushort_t* __restrict__ vpw_bf,
    const float* __restrict__ wih0, ushort_t* __restrict__ wih0_bf,
    const float* __restrict__ wih2, ushort_t* __restrict__ wih2_bf,
    const float* __restrict__ ainw, ushort_t* __restrict__ ainw_bf,
    const float* __restrict__ aoutw, ushort_t* __restrict__ aoutw_bf,
    const float* __restrict__ ow, ushort_t* __restrict__ ow_bf,
    float* __restrict__ vpf, float* __restrict__ flags, float* __restrict__ ringA0,
    float* __restrict__ ringB0) {
  int b = (int)blockIdx.x;
  int tid = (int)threadIdx.x;
  if (b < 2048) { cvt_blk(vpw, vpw_bf, b, tid); return; }
  if (b < 3072) { cvt_blk(wih0, wih0_bf, b - 2048, tid); return; }
  if (b < 4096) { cvt_blk(wih2, wih2_bf, b - 3072, tid); return; }
  if (b < 4864) { cvt_blk(ainw, ainw_bf, b - 4096, tid); return; }
  if (b < 5120) { cvt_blk(aoutw, aoutw_bf, b - 4864, tid); return; }
  if (b < 10120) { cvt_blk(ow, ow_bf, b - 5120, tid); return; }
  float4 z = {0.f, 0.f, 0.f, 0.f};
  if (b < 12680) { reinterpret_cast<float4*>(vpf)[(b - 10120) * 256 + tid] = z; return; }
  if (b < 12681) { reinterpret_cast<float4*>(flags)[tid] = z; return; }
  if (b < 12713) { reinterpret_cast<float4*>(ringA0)[(b - 12681) * 256 + tid] = z; return; }
  reinterpret_cast<float4*>(ringB0)[(b - 12713) * 256 + tid] = z;
}

// ---------------- whh: split (hi+lo) + gate-tile permute, 4 layers fused ------------
__global__ __launch_bounds__(64) void permute_split_whh4(
    const float* __restrict__ s0, ushort_t* __restrict__ h0, ushort_t* __restrict__ l0,
    const float* __restrict__ s1, ushort_t* __restrict__ h1, ushort_t* __restrict__ l1,
    const float* __restrict__ s2, ushort_t* __restrict__ h2, ushort_t* __restrict__ l2,
    const float* __restrict__ s3, ushort_t* __restrict__ h3, ushort_t* __restrict__ l3) {
  int layer = blockIdx.y;
  const float* src = (layer == 0) ? s0 : (layer == 1) ? s1 : (layer == 2) ? s2 : s3;
  ushort_t* hi = (layer == 0) ? h0 : (layer == 1) ? h1 : (layer == 2) ? h2 : h3;
  ushort_t* lo = (layer == 0) ? l0 : (layer == 1) ? l1 : (layer == 2) ? l2 : l3;
  int p = blockIdx.x;  // 0..2047
  int tile = p >> 4, r = p & 15, gate = r >> 2, sc = r & 3;
  const float* s = src + ((size_t)(gate * H_ + tile * 4 + sc)) * H_;
  int i = threadIdx.x * 8;
  float4 v0 = *reinterpret_cast<const float4*>(s + i);
  float4 v1 = *reinterpret_cast<const float4*>(s + i + 4);
  ushort_t* hp = hi + (size_t)p * H_ + i;
  ushort_t* lp = lo + (size_t)p * H_ + i;
  ushort4 rh0, rl0, rh1, rl1;
  rh0.x = f2bf(v0.x); rl0.x = f2bf(v0.x - bf2f(rh0.x));
  rh0.y = f2bf(v0.y); rl0.y = f2bf(v0.y - bf2f(rh0.y));
  rh0.z = f2bf(v0.z); rl0.z = f2bf(v0.z - bf2f(rh0.z));
  rh0.w = f2bf(v0.w); rl0.w = f2bf(v0.w - bf2f(rh0.w));
  rh1.x = f2bf(v1.x); rl1.x = f2bf(v1.x - bf2f(rh1.x));
  rh1.y = f2bf(v1.y); rl1.y = f2bf(v1.y - bf2f(rh1.y));
  rh1.z = f2bf(v1.z); rl1.z = f2bf(v1.z - bf2f(rh1.z));
  rh1.w = f2bf(v1.w); rl1.w = f2bf(v1.w - bf2f(rh1.w));
  reinterpret_cast<ushort4*>(hp)[0] = rh0;
  reinterpret_cast<ushort4*>(hp)[1] = rh1;
  reinterpret_cast<ushort4*>(lp)[0] = rl0;
  reinterpret_cast<ushort4*>(lp)[1] = rl1;
}

// wih permute (layers 1,3 fused)
__global__ __launch_bounds__(64) void permute_cvt_wih2(const float* __restrict__ s1,
                                                       ushort_t* __restrict__ d1,
                                                       const float* __restrict__ s3,
                                                       ushort_t* __restrict__ d3) {
  const float* src = blockIdx.y ? s3 : s1;
  ushort_t* hi = blockIdx.y ? d3 : d1;
  int p = blockIdx.x;
  int tile = p >> 4, r = p & 15, gate = r >> 2, sc = r & 3;
  const float* s = src + ((size_t)(gate * H_ + tile * 4 + sc)) * H_;
  int i = threadIdx.x * 8;
  float4 v0 = *reinterpret_cast<const float4*>(s + i);
  float4 v1 = *reinterpret_cast<const float4*>(s + i + 4);
  ushort_t* hp = hi + (size_t)p * H_ + i;
  ushort4 rh0, rh1;
  rh0.x = f2bf(v0.x); rh0.y = f2bf(v0.y); rh0.z = f2bf(v0.z); rh0.w = f2bf(v0.w);
  rh1.x = f2bf(v1.x); rh1.y = f2bf(v1.y); rh1.z = f2bf(v1.z); rh1.w = f2bf(v1.w);
  reinterpret_cast<ushort4*>(hp)[0] = rh0;
  reinterpret_cast<ushort4*>(hp)[1] = rh1;
}

__global__ __launch_bounds__(256) void combine_bias_perm2(const float* __restrict__ bih1,
                                                          const float* __restrict__ bhh1,
                                                          float* __restrict__ bc1,
                                                          const float* __restrict__ bih3,
                                                          const float* __restrict__ bhh3,
                                                          float* __restrict__ bc3) {
  const float* bih = blockIdx.y ? bih3 : bih1;
  const float* bhh = blockIdx.y ? bhh3 : bhh1;
  float* bc = blockIdx.y ? bc3 : bc1;
  int q = blockIdx.x * 256 + threadIdx.x;  // 0..2047
  int tile = q >> 4, r = q & 15, gate = r >> 2, sc = r & 3;
  int src = gate * H_ + tile * 4 + sc;
  bc[q] = bih[src] + bhh[src];
}

// ---------------- embedding gather -> bf16 ----------------
__global__ __launch_bounds__(256) void gather_embed(const float* __restrict__ tab,
                                                    const int* __restrict__ cap,
                                                    ushort_t* __restrict__ outp) {
  int t = blockIdx.x;
  int b = blockIdx.y;
  int tok = cap[b * 20 + t];
  const float* src = tab + (size_t)tok * H_;
  ushort_t* dst = outp + ((size_t)(b * TD_ + t)) * H_;
  int i = threadIdx.x;
  float2 v = reinterpret_cast<const float2*>(src)[i];
  ushort2 r;
  r.x = f2bf(v.x);
  r.y = f2bf(v.y);
  reinterpret_cast<ushort2*>(dst)[i] = r;
}

// ---------------- small-tile GEMM (64x64/block) ----------------
__device__ __forceinline__ void store_c(float* C, size_t idx, float v) { C[idx] = v; }
__device__ __forceinline__ void store_c(ushort_t* C, size_t idx, float v) { C[idx] = f2bf(v); }

template <typename OT>
__global__ __launch_bounds__(256) void gemm_nt_mfma(const ushort_t* __restrict__ A,
                                                    const ushort_t* __restrict__ W,
                                                    const float* __restrict__ bias1,
                                                    const float* __restrict__ bias2,
                                                    OT* __restrict__ C, int M, int N, int K) {
  int tid = threadIdx.x;
  int l = tid & 63, w = tid >> 6;
  int wm = w >> 1, wn = w & 1;
  int row0 = blockIdx.y * 64 + wm * 32;
  int col0 = blockIdx.x * 64 + wn * 32;
  int lr = l & 15;
  int kb = (l >> 4) << 3;
  int ar0 = row0 + lr, ar1 = row0 + 16 + lr;
  int wr0 = col0 + lr, wr1 = col0 + 16 + lr;
  bool aok0 = ar0 < M, aok1 = ar1 < M;
  bool wok0 = wr0 < N, wok1 = wr1 < N;
  f32x4 acc00 = {0.f, 0.f, 0.f, 0.f}, acc01 = acc00, acc10 = acc00, acc11 = acc00;
#pragma unroll 2
  for (int k0 = 0; k0 < K; k0 += 32) {
    int k = k0 + kb;
    short8 a0 = aok0 ? *reinterpret_cast<const short8*>(A + (size_t)ar0 * K + k) : zero8();
    short8 a1 = aok1 ? *reinterpret_cast<const short8*>(A + (size_t)ar1 * K + k) : zero8();
    short8 b0 = wok0 ? *reinterpret_cast<const short8*>(W + (size_t)wr0 * K + k) : zero8();
    short8 b1 = wok1 ? *reinterpret_cast<const short8*>(W + (size_t)wr1 * K + k) : zero8();
    acc00 = __builtin_amdgcn_mfma_f32_16x16x32_bf16(a0, b0, acc00, 0, 0, 0);
    acc01 = __builtin_amdgcn_mfma_f32_16x16x32_bf16(a0, b1, acc01, 0, 0, 0);
    acc10 = __builtin_amdgcn_mfma_f32_16x16x32_bf16(a1, b0, acc10, 0, 0, 0);
    acc11 = __builtin_amdgcn_mfma_f32_16x16x32_bf16(a1, b1, acc11, 0, 0, 0);
  }
  int rb = (l >> 4) << 2;
#pragma unroll
  for (int i = 0; i < 2; ++i) {
#pragma unroll
    for (int v = 0; v < 4; ++v) {
      int r = row0 + i * 16 + rb + v;
      if (r < M) {
#pragma unroll
        for (int j = 0; j < 2; ++j) {
          int cc = col0 + j * 16 + lr;
          if (cc < N) {
            float av;
            if (i == 0) av = (j == 0) ? acc00[v] : acc01[v];
            else        av = (j == 0) ? acc10[v] : acc11[v];
            if (bias1) av += bias1[cc];
            if (bias2) av += bias2[cc];
            store_c(C, (size_t)r * N + cc, av);
          }
        }
      }
    }
  }
}

// K and V projections fused: blockIdx.z selects weight slice + output
__global__ __launch_bounds__(256) void gemm_kv(const ushort_t* __restrict__ A,
                                               const ushort_t* __restrict__ ainw,
                                               const float* __restrict__ ainb,
                                               float* __restrict__ Kf, float* __restrict__ Vf) {
  int z = blockIdx.z;
  const ushort_t* W = ainw + (size_t)(1 + z) * H_ * H_;
  const float* bias = ainb + (1 + z) * H_;
  float* C = z ? Vf : Kf;
  int tid = threadIdx.x;
  int l = tid & 63, w = tid >> 6;
  int wm = w >> 1, wn = w & 1;
  int row0 = blockIdx.y * 64 + wm * 32;
  int col0 = blockIdx.x * 64 + wn * 32;
  int lr = l & 15;
  int kb = (l >> 4) << 3;
  f32x4 acc00 = {0.f, 0.f, 0.f, 0.f}, acc01 = acc00, acc10 = acc00, acc11 = acc00;
  const ushort_t* a0p = A + (size_t)(row0 + lr) * H_ + kb;
  const ushort_t* a1p = A + (size_t)(row0 + 16 + lr) * H_ + kb;
  const ushort_t* b0p = W + (size_t)(col0 + lr) * H_ + kb;
  const ushort_t* b1p = W + (size_t)(col0 + 16 + lr) * H_ + kb;
#pragma unroll 2
  for (int k0 = 0; k0 < H_; k0 += 32) {
    short8 a0 = *reinterpret_cast<const short8*>(a0p + k0);
    short8 a1 = *reinterpret_cast<const short8*>(a1p + k0);
    short8 b0 = *reinterpret_cast<const short8*>(b0p + k0);
    short8 b1 = *reinterpret_cast<const short8*>(b1p + k0);
    acc00 = __builtin_amdgcn_mfma_f32_16x16x32_bf16(a0, b0, acc00, 0, 0, 0);
    acc01 = __builtin_amdgcn_mfma_f32_16x16x32_bf16(a0, b1, acc01, 0, 0, 0);
    acc10 = __builtin_amdgcn_mfma_f32_16x16x32_bf16(a1, b0, acc10, 0, 0, 0);
    acc11 = __builtin_amdgcn_mfma_f32_16x16x32_bf16(a1, b1, acc11, 0, 0, 0);
  }
  int rb = (l >> 4) << 2;
#pragma unroll
  for (int i = 0; i < 2; ++i)
#pragma unroll
    for (int v = 0; v < 4; ++v) {
      int r = row0 + i * 16 + rb + v;
#pragma unroll
      for (int j = 0; j < 2; ++j) {
        int cc = col0 + j * 16 + lr;
        float av;
        if (i == 0) av = (j == 0) ? acc00[v] : acc01[v];
        else        av = (j == 0) ? acc10[v] : acc11[v];
        C[(size_t)r * H_ + cc] = av + bias[cc];
      }
    }
}

// ---------------- big-tile GEMM (64 rows x 256 cols / block) ----------------
template <typename OT>
__global__ __launch_bounds__(256) void gemm_nt_big(const ushort_t* __restrict__ A,
                                                   const ushort_t* __restrict__ W,
                                                   const float* __restrict__ bias1,
                                                   const float* __restrict__ bias2,
                                                   OT* __restrict__ C, int M, int N, int K) {
  int tid = threadIdx.x;
  int l = tid & 63, w = tid >> 6;
  int row0 = blockIdx.y * 64;
  int col0 = blockIdx.x * 256 + w * 64;
  int lr = l & 15, kb = (l >> 4) << 3;
  f32x4 acc[4][4];
#pragma unroll
  for (int i = 0; i < 4; ++i)
#pragma unroll
    for (int j = 0; j < 4; ++j) acc[i][j] = (f32x4){0.f, 0.f, 0.f, 0.f};
  const ushort_t* aps[4];
  const ushort_t* wps[4];
  bool wok[4];
#pragma unroll
  for (int fi = 0; fi < 4; ++fi) aps[fi] = A + (size_t)(row0 + fi * 16 + lr) * K + kb;
#pragma unroll
  for (int fj = 0; fj < 4; ++fj) {
    int wr = col0 + fj * 16 + lr;
    wok[fj] = wr < N;
    wps[fj] = W + (size_t)(wok[fj] ? wr : 0) * K + kb;
  }
#pragma unroll 2
  for (int k0 = 0; k0 < K; k0 += 32) {
    short8 af[4], bf[4];
#pragma unroll
    for (int fi = 0; fi < 4; ++fi) af[fi] = *reinterpret_cast<const short8*>(aps[fi] + k0);
#pragma unroll
    for (int fj = 0; fj < 4; ++fj)
      bf[fj] = wok[fj] ? *reinterpret_cast<const short8*>(wps[fj] + k0) : zero8();
#pragma unroll
    for (int fi = 0; fi < 4; ++fi)
#pragma unroll
      for (int fj = 0; fj < 4; ++fj)
        acc[fi][fj] = __builtin_amdgcn_mfma_f32_16x16x32_bf16(af[fi], bf[fj], acc[fi][fj], 0, 0, 0);
  }
  int rb = (l >> 4) << 2;
#pragma unroll
  for (int fi = 0; fi < 4; ++fi) {
#pragma unroll
    for (int v = 0; v < 4; ++v) {
      int r = row0 + fi * 16 + rb + v;
#pragma unroll
      for (int fj = 0; fj < 4; ++fj) {
        int cc = col0 + fj * 16 + lr;
        if (cc < N) {
          float av = acc[fi][fj][v];
          if (bias1) av += bias1[cc];
          if (bias2) av += bias2[cc];
          store_c(C, (size_t)r * N + cc, av);
        }
      }
    }
  }
}

// ---------------- split-K big GEMM with fp32 atomic accumulation ----------------
__global__ __launch_bounds__(256) void gemm_nt_big_split(const ushort_t* __restrict__ A,
                                                         const ushort_t* __restrict__ W,
                                                         float* __restrict__ C, int M, int N,
                                                         int K, int kc) {
  int tid = threadIdx.x;
  int l = tid & 63, w = tid >> 6;
  int row0 = blockIdx.y * 64;
  int col0 = blockIdx.x * 256 + w * 64;
  int lr = l & 15, kb = (l >> 4) << 3;
  int kbeg = blockIdx.z * kc;
  f32x4 acc[4][4];
#pragma unroll
  for (int i = 0; i < 4; ++i)
#pragma unroll
    for (int j = 0; j < 4; ++j) acc[i][j] = (f32x4){0.f, 0.f, 0.f, 0.f};
  const ushort_t* aps[4];
  const ushort_t* wps[4];
#pragma unroll
  for (int fi = 0; fi < 4; ++fi)
    aps[fi] = A + (size_t)(row0 + fi * 16 + lr) * K + kbeg + kb;
#pragma unroll
  for (int fj = 0; fj < 4; ++fj)
    wps[fj] = W + (size_t)(col0 + fj * 16 + lr) * K + kbeg + kb;
#pragma unroll 2
  for (int k0 = 0; k0 < kc; k0 += 32) {
    short8 af[4], bf[4];
#pragma unroll
    for (int fi = 0; fi < 4; ++fi) af[fi] = *reinterpret_cast<const short8*>(aps[fi] + k0);
#pragma unroll
    for (int fj = 0; fj < 4; ++fj) bf[fj] = *reinterpret_cast<const short8*>(wps[fj] + k0);
#pragma unroll
    for (int fi = 0; fi < 4; ++fi)
#pragma unroll
      for (int fj = 0; fj < 4; ++fj)
        acc[fi][fj] = __builtin_amdgcn_mfma_f32_16x16x32_bf16(af[fi], bf[fj], acc[fi][fj], 0, 0, 0);
  }
  int rb = (l >> 4) << 2;
#pragma unroll
  for (int fi = 0; fi < 4; ++fi)
#pragma unroll
    for (int v = 0; v < 4; ++v) {
      int r = row0 + fi * 16 + rb + v;
#pragma unroll
      for (int fj = 0; fj < 4; ++fj) {
        int cc = col0 + fj * 16 + lr;
        atomicAdd(&C[(size_t)r * N + cc], acc[fi][fj][v]);
      }
    }
}

// add column-bias + cvt to bf16 (vproj epilogue)
__global__ __launch_bounds__(256) void bias_cvt_bf16(const float* __restrict__ in,
                                                     const float* __restrict__ bias,
                                                     ushort_t* __restrict__ outp, int ncols,
                                                     int n4) {
  int i = blockIdx.x * 256 + threadIdx.x;
  if (i < n4) {
    float4 v = reinterpret_cast<const float4*>(in)[i];
    int col = (i * 4) & (ncols - 1);
    float4 bv = *reinterpret_cast<const float4*>(bias + col);
    ushort4 r;
    r.x = f2bf(v.x + bv.x); r.y = f2bf(v.y + bv.y);
    r.z = f2bf(v.z + bv.z); r.w = f2bf(v.w + bv.w);
    reinterpret_cast<ushort4*>(outp)[i] = r;
  }
}

// ---------------- epoch-flag wait: DENSE flags (8 cache lines / array) ----------------
// Flags are 4B apart: one poll iteration touches 8 lines (vs 128 at 64B stride) so the
// wave's MALL fill batch is 1 deep, not 4. Producer stores hit distinct bytes -> safe.
__device__ __forceinline__ void wait_flags2(const int* __restrict__ fA, int tA,
                                            const int* __restrict__ fB, int tB, int tid) {
  if (tid < 64) {
    for (;;) {
      int a0 = __hip_atomic_load(fA + tid, __ATOMIC_RELAXED, __HIP_MEMORY_SCOPE_AGENT);
      int a1 = __hip_atomic_load(fA + tid + 64, __ATOMIC_RELAXED, __HIP_MEMORY_SCOPE_AGENT);
      bool ok = (a0 >= tA) && (a1 >= tA);
      if (fB) {
        int b0 = __hip_atomic_load(fB + tid, __ATOMIC_RELAXED, __HIP_MEMORY_SCOPE_AGENT);
        int b1 = __hip_atomic_load(fB + tid + 64, __ATOMIC_RELAXED, __HIP_MEMORY_SCOPE_AGENT);
        ok = ok && (b0 >= tB) && (b1 >= tB);
      }
      if (__all(ok)) break;
      __builtin_amdgcn_s_sleep(2);
    }
  }
  __syncthreads();
}

// ---------------- persistent diagonal LSTM pair (R6 core + dense flags) ----------------
__global__ __launch_bounds__(512, 2) void lstm_ring(
    const float* __restrict__ xg, const ushort_t* __restrict__ whhA_hi,
    const ushort_t* __restrict__ whhA_lo, const ushort_t* __restrict__ whhB_hi,
    const ushort_t* __restrict__ whhB_lo, const ushort_t* __restrict__ wihB,
    const float* __restrict__ bcB, unsigned int* __restrict__ ringA,
    unsigned int* __restrict__ ringB, ushort_t* __restrict__ hsB, int T,
    int* __restrict__ flagA, int* __restrict__ flagB) {
  __shared__ float gbuf[2][64][17];
  const int role = (int)(blockIdx.x >> 7);  // 0 = layer A, 1 = layer B
  const int tile = (int)(blockIdx.x & 127);
  const int tid = (int)threadIdx.x;
  const int g2 = tid >> 8;                 // K-half
  const int u = tid & 255;
  const int l = u & 63, w = u >> 6;
  const int lr = l & 15, kq = l >> 4;
  const int kb = g2 * 256 + (kq << 3);     // K element offset
  const int arow = (w << 4) + lr;
  const int prow = tile * 16 + lr;
  const int row = tid >> 2, s = tid & 3;   // gate phase (tid<256)
  const int col = (tile << 2) + s;
  unsigned int* ring_own = role ? ringB : ringA;
  int* flag_own = (role ? flagB : flagA) + tile;  // dense: 4B apart

  short8 wb[8], wbl[8];
  {
    const ushort_t* bp = (role ? whhB_hi : whhA_hi) + (size_t)prow * H_ + kb;
    const ushort_t* blp = (role ? whhB_lo : whhA_lo) + (size_t)prow * H_ + kb;
#pragma unroll
    for (int i = 0; i < 8; ++i) {
      wb[i] = *reinterpret_cast<const short8*>(bp + i * 32);
      wbl[i] = *reinterpret_cast<const short8*>(blp + i * 32);
    }
  }
  const ushort_t* wpp = wihB + (size_t)prow * H_ + kb;
  float bci = 0.f, bcf = 0.f, bcg = 0.f, bco = 0.f;
  if (role && tid < 256) {
    bci = bcB[tile * 16 + 0 + s];
    bcf = bcB[tile * 16 + 4 + s];
    bcg = bcB[tile * 16 + 8 + s];
    bco = bcB[tile * 16 + 12 + s];
  }
  float creg = 0.f;
  for (int t = 0; t < T; ++t) {
    float xgi = 0.f, xgf = 0.f, xgg = 0.f, xgo = 0.f;
    if (!role && tid < 256) {
      size_t xb = ((size_t)row * T + t) * (size_t)G4_ + col;
      xgi = xg[xb]; xgf = xg[xb + 512]; xgg = xg[xb + 1024]; xgo = xg[xb + 1536];
    }
    if (role == 0) {
      if (t > 0) wait_flags2(flagA, t, nullptr, 0, tid);
      else __syncthreads();
    } else {
      wait_flags2(flagA, t + 1, (t > 0) ? flagB : nullptr, t, tid);
    }
    const unsigned int* rh = ring_own + (size_t)t * HN_ + (size_t)arow * H_ + kb;
    f32x4 a0 = {0.f, 0.f, 0.f, 0.f}, a1 = a0, a2 = a0, a3 = a0;
    if (role == 0) {
      uint4 q[16];
#pragma unroll
      for (int i = 0; i < 8; ++i) {
        q[2 * i] = *reinterpret_cast<const uint4*>(rh + i * 32);
        q[2 * i + 1] = *reinterpret_cast<const uint4*>(rh + i * 32 + 4);
      }
#pragma unroll
      for (int i = 0; i < 8; ++i) {
        short8 a = unpack_hi(q[2 * i], q[2 * i + 1]);
        short8 al = unpack_lo(q[2 * i], q[2 * i + 1]);
        a0 = __builtin_amdgcn_mfma_f32_16x16x32_bf16(a, wb[i], a0, 0, 0, 0);
        a1 = __builtin_amdgcn_mfma_f32_16x16x32_bf16(al, wb[i], a1, 0, 0, 0);
        a2 = __builtin_amdgcn_mfma_f32_16x16x32_bf16(a, wbl[i], a2, 0, 0, 0);
      }
    } else {
      const unsigned int* rx = ringA + (size_t)(t + 1) * HN_ + (size_t)arow * H_ + kb;
      uint4 q[16], p[16];
#pragma unroll
      for (int i = 0; i < 8; ++i) {
        q[2 * i] = *reinterpret_cast<const uint4*>(rh + i * 32);
        q[2 * i + 1] = *reinterpret_cast<const uint4*>(rh + i * 32 + 4);
      }
#pragma unroll
      for (int i = 0; i < 8; ++i) {
        p[2 * i] = *reinterpret_cast<const uint4*>(rx + i * 32);
        p[2 * i + 1] = *reinterpret_cast<const uint4*>(rx + i * 32 + 4);
      }
#pragma unroll
      for (int i = 0; i < 8; ++i) {
        short8 a = unpack_hi(q[2 * i], q[2 * i + 1]);
        short8 al = unpack_lo(q[2 * i], q[2 * i + 1]);
        short8 x = unpack_hi(p[2 * i], p[2 * i + 1]);
        short8 wx = *reinterpret_cast<const short8*>(wpp + i * 32);
        a0 = __builtin_amdgcn_mfma_f32_16x16x32_bf16(a, wb[i], a0, 0, 0, 0);
        a1 = __builtin_amdgcn_mfma_f32_16x16x32_bf16(al, wb[i], a1, 0, 0, 0);
        a2 = __builtin_amdgcn_mfma_f32_16x16x32_bf16(a, wbl[i], a2, 0, 0, 0);
        a3 = __builtin_amdgcn_mfma_f32_16x16x32_bf16(x, wx, a3, 0, 0, 0);
      }
    }
    f32x4 acc = (a0 + a1) + (a2 + a3);
    const int rb = (w << 4) + (kq << 2);
#pragma unroll
    for (int v = 0; v < 4; ++v) gbuf[g2][rb + v][lr] = acc[v];
    __syncthreads();
    if (tid < 256) {
      float gi = gbuf[0][row][0 + s] + gbuf[1][row][0 + s];
      float gf = gbuf[0][row][4 + s] + gbuf[1][row][4 + s];
      float gg = gbuf[0][row][8 + s] + gbuf[1][row][8 + s];
      float go = gbuf[0][row][12 + s] + gbuf[1][row][12 + s];
      if (role) {
        gi += bci; gf += bcf; gg += bcg; go += bco;
      } else {
        gi += xgi; gf += xgf; gg += xgg; go += xgo;
      }
      float cv = sigmoidf_(gf) * creg + sigmoidf_(gi) * tanhf(gg);
      float hv = sigmoidf_(go) * tanhf(cv);
      creg = cv;
      ushort_t hh = f2bf(hv);
      ushort_t hl = f2bf(hv - bf2f(hh));
      unsigned int pk = (unsigned int)hh | ((unsigned int)hl << 16);
      __hip_atomic_store(ring_own + (size_t)(t + 1) * HN_ + (size_t)row * H_ + col, pk,
                         __ATOMIC_RELAXED, __HIP_MEMORY_SCOPE_AGENT);
      if (role) hsB[((size_t)row * T + t) * H_ + col] = hh;
    }
    __syncthreads();  // vmcnt(0) drain of all waves' write-through stores, then barrier
    if (tid == 0)
      __hip_atomic_store(flag_own, t + 1, __ATOMIC_RELAXED, __HIP_MEMORY_SCOPE_AGENT);
  }
}

// ---------------- MHA (fp32) ----------------
__global__ __launch_bounds__(256) void mha_kernel(const float* __restrict__ Qf,
                                                  const float* __restrict__ Kf,
                                                  const float* __restrict__ Vf,
                                                  ushort_t* __restrict__ attnout) {
  __shared__ float Qs[19][132];
  __shared__ float Ks[80][132];
  __shared__ float Ss[19][80];
  int h = blockIdx.x, b = blockIdx.y;
  int tid = threadIdx.x;
  for (int idx = tid; idx < 19 * 128; idx += 256) {
    int q = idx >> 7, d = idx & 127;
    Qs[q][d] = Qf[((size_t)(b * TD_ + q)) * H_ + h * 128 + d];
  }
  for (int idx = tid; idx < 80 * 128; idx += 256) {
    int k = idx >> 7, d = idx & 127;
    Ks[k][d] = Kf[((size_t)(b * TV_ + k)) * H_ + h * 128 + d];
  }
  __syncthreads();
  for (int u = tid; u < 240; u += 256) {
    int k = u / 3, qo = u % 3;
    int q0 = qo * 8;
    int nq = (qo == 2) ? 3 : 8;
    float s[8] = {0.f, 0.f, 0.f, 0.f, 0.f, 0.f, 0.f, 0.f};
    for (int d = 0; d < 128; d += 4) {
      float4 kv = *reinterpret_cast<const float4*>(&Ks[k][d]);
#pragma unroll
      for (int qi = 0; qi < 8; ++qi) {
        if (qi < nq) {
          float4 qv = *reinterpret_cast<const float4*>(&Qs[q0 + qi][d]);
          s[qi] += qv.x * kv.x + qv.y * kv.y + qv.z * kv.z + qv.w * kv.w;
        }
      }
    }
    for (int qi = 0; qi < nq; ++qi) Ss[q0 + qi][k] = s[qi] * 0.08838834764831845f;
  }
  __syncthreads();
  if (tid < 19) {
    float m = -1e30f;
    for (int k = 0; k < 80; ++k) m = fmaxf(m, Ss[tid][k]);
    float sum = 0.f;
    for (int k = 0; k < 80; ++k) {
      float e = expf(Ss[tid][k] - m);
      Ss[tid][k] = e;
      sum += e;
    }
    float inv = 1.0f / sum;
    for (int k = 0; k < 80; ++k) Ss[tid][k] *= inv;
  }
  __syncthreads();
  for (int u = tid; u < 160; u += 256) {
    int qp = u / 16, d0 = (u % 16) * 8;
    int q0 = qp * 2;
    int nq = (q0 + 1 < 19) ? 2 : 1;
    float o0[8] = {0.f, 0.f, 0.f, 0.f, 0.f, 0.f, 0.f, 0.f};
    float o1[8] = {0.f, 0.f, 0.f, 0.f, 0.f, 0.f, 0.f, 0.f};
#pragma unroll 4
    for (int k = 0; k < 80; ++k) {
      const float* vp = Vf + ((size_t)(b * TV_ + k)) * H_ + h * 128 + d0;
      float4 v0 = *reinterpret_cast<const float4*>(vp);
      float4 v1 = *reinterpret_cast<const float4*>(vp + 4);
      float p0 = Ss[q0][k];
      o0[0] += p0 * v0.x; o0[1] += p0 * v0.y; o0[2] += p0 * v0.z; o0[3] += p0 * v0.w;
      o0[4] += p0 * v1.x; o0[5] += p0 * v1.y; o0[6] += p0 * v1.z; o0[7] += p0 * v1.w;
      if (nq == 2) {
        float p1 = Ss[q0 + 1][k];
        o1[0] += p1 * v0.x; o1[1] += p1 * v0.y; o1[2] += p1 * v0.z; o1[3] += p1 * v0.w;
        o1[4] += p1 * v1.x; o1[5] += p1 * v1.y; o1[6] += p1 * v1.z; o1[7] += p1 * v1.w;
      }
    }
    for (int j = 0; j < 8; ++j)
      attnout[((size_t)(b * TD_ + q0)) * H_ + h * 128 + d0 + j] = f2bf(o0[j]);
    if (nq == 2)
      for (int j = 0; j < 8; ++j)
        attnout[((size_t)(b * TD_ + q0 + 1)) * H_ + h * 128 + d0 + j] = f2bf(o1[j]);
  }
}

// ---------------- host ----------------
extern "C" void kernel_launch(void* const* d_in, const int* in_sizes, int n_in, void* d_out,
                              int out_size, void* d_ws, size_t ws_size, hipStream_t stream) {
  const float* video = (const float*)d_in[0];
  const int* captions = (const int*)d_in[1];
  const float* vpw = (const float*)d_in[2];
  const float* vpb = (const float*)d_in[3];
  const float* emb_table = (const float*)d_in[4];
  const float* wih[4] = {(const float*)d_in[5], (const float*)d_in[9], (const float*)d_in[13],
                         (const float*)d_in[17]};
  const float* whh[4] = {(const float*)d_in[6], (const float*)d_in[10], (const float*)d_in[14],
                         (const float*)d_in[18]};
  const float* bih[4] = {(const float*)d_in[7], (const float*)d_in[11], (const float*)d_in[15],
                         (const float*)d_in[19]};
  const float* bhh[4] = {(const float*)d_in[8], (const float*)d_in[12], (const float*)d_in[16],
                         (const float*)d_in[20]};
  const float* a_inw = (const float*)d_in[21];
  const float* a_inb = (const float*)d_in[22];
  const float* a_outw = (const float*)d_in[23];
  const float* a_outb = (const float*)d_in[24];
  const float* ow = (const float*)d_in[25];
  const float* ob = (const float*)d_in[26];
  float* out = (float*)d_out;

  char* ws = (char*)d_ws;
  size_t o = 0;
  auto take = [&](size_t bytes) {
    size_t cur = o;
    o += (bytes + 255) & ~(size_t)255;
    return cur;
  };
  const size_t o_vpw = take((size_t)H_ * VD_ * 2);
  size_t o_wih_std[4], o_whhp_hi[4], o_whhp_lo[4], o_wihp[4], o_bc[4];
  for (int i = 0; i < 4; ++i) {
    o_wih_std[i] = (i == 0 || i == 2) ? take((size_t)G4_ * H_ * 2) : 0;
    o_whhp_hi[i] = take((size_t)G4_ * H_ * 2);
    o_whhp_lo[i] = take((size_t)G4_ * H_ * 2);
    o_wihp[i] = (i == 1 || i == 3) ? take((size_t)G4_ * H_ * 2) : 0;
    o_bc[i] = (i == 1 || i == 3) ? take((size_t)G4_ * 4) : 0;
  }
  const size_t o_ainw = take((size_t)3 * H_ * H_ * 2);
  const size_t o_aoutw = take((size_t)H_ * H_ * 2);
  const size_t o_ow = take((size_t)NV_ * H_ * 2);
  const size_t o_vproj = take((size_t)B_ * TV_ * H_ * 2);
  const size_t o_xg = take((size_t)B_ * TV_ * G4_ * 4);  // video_bf overlay, then xg, then Q/K/V
  const size_t o_hse1 = take((size_t)B_ * TV_ * H_ * 2);
  const size_t o_emb = take((size_t)B_ * TD_ * H_ * 2);
  const size_t o_attn = take((size_t)B_ * TD_ * H_ * 2);
  const size_t o_attd = take((size_t)B_ * TD_ * H_ * 2);
  const size_t o_hsd1 = take((size_t)B_ * TD_ * H_ * 2);
  const size_t o_flags = take(4096);  // 4 dense flag arrays (128 ints each) + pad
  const size_t o_vpf = take((size_t)B_ * TV_ * H_ * 4);  // vproj fp32 accum
  const size_t o_ringA = take((size_t)(TV_ + 1) * HN_ * 4);
  const size_t o_ringB = take((size_t)(TV_ + 1) * HN_ * 4);

  ushort_t* vpw_bf = (ushort_t*)(ws + o_vpw);
  ushort_t* ainw_bf = (ushort_t*)(ws + o_ainw);
  ushort_t* aoutw_bf = (ushort_t*)(ws + o_aoutw);
  ushort_t* ow_bf = (ushort_t*)(ws + o_ow);
  ushort_t* vproj_bf = (ushort_t*)(ws + o_vproj);
  float* xg = (float*)(ws + o_xg);
  ushort_t* video_bf = (ushort_t*)(ws + o_xg);  // overlay
  ushort_t* hse1 = (ushort_t*)(ws + o_hse1);
  ushort_t* emb_bf = (ushort_t*)(ws + o_emb);
  ushort_t* attn_bf = (ushort_t*)(ws + o_attn);
  ushort_t* attd_bf = (ushort_t*)(ws + o_attd);
  ushort_t* hsd1 = (ushort_t*)(ws + o_hsd1);
  float* Qf = (float*)(ws + o_xg);
  float* Kf = (float*)(ws + o_xg + 2490368);
  float* Vf = (float*)(ws + o_xg + 2490368 + 10485760);
  int* flagA0 = (int*)(ws + o_flags);
  int* flagB0 = flagA0 + 128;
  int* flagA1 = flagA0 + 256;
  int* flagB1 = flagA0 + 384;
  float* vpf = (float*)(ws + o_vpf);
  unsigned int* ringA = (unsigned int*)(ws + o_ringA);
  unsigned int* ringB = (unsigned int*)(ws + o_ringB);

  // 1. video cvt (big, standalone)
  cvt_f32_bf16<<<dim3(20480), dim3(256), 0, stream>>>(video, video_bf,
                                                      (int)((size_t)B_ * TV_ * VD_ / 4));
  // 2. fused small cvts + zero-fills
  prep_small<<<dim3(12745), dim3(256), 0, stream>>>(
      vpw, vpw_bf, wih[0], (ushort_t*)(ws + o_wih_std[0]), wih[2],
      (ushort_t*)(ws + o_wih_std[2]), a_inw, ainw_bf, a_outw, aoutw_bf, ow, ow_bf, vpf,
      (float*)(ws + o_flags), (float*)ringA, (float*)ringB);
  // 3. whh permute+split, 4 layers fused
  permute_split_whh4<<<dim3(G4_, 4), dim3(64), 0, stream>>>(
      whh[0], (ushort_t*)(ws + o_whhp_hi[0]), (ushort_t*)(ws + o_whhp_lo[0]), whh[1],
      (ushort_t*)(ws + o_whhp_hi[1]), (ushort_t*)(ws + o_whhp_lo[1]), whh[2],
      (ushort_t*)(ws + o_whhp_hi[2]), (ushort_t*)(ws + o_whhp_lo[2]), whh[3],
      (ushort_t*)(ws + o_whhp_hi[3]), (ushort_t*)(ws + o_whhp_lo[3]));
  // 4. wih permute, layers 1+3 fused
  permute_cvt_wih2<<<dim3(G4_, 2), dim3(64), 0, stream>>>(
      wih[1], (ushort_t*)(ws + o_wihp[1]), wih[3], (ushort_t*)(ws + o_wihp[3]));
  // 5. bias combine, layers 1+3 fused
  combine_bias_perm2<<<dim3(G4_ / 256, 2), dim3(256), 0, stream>>>(
      bih[1], bhh[1], (float*)(ws + o_bc[1]), bih[3], bhh[3], (float*)(ws + o_bc[3]));

  // 6-7. vproj: split-K x4 atomic fp32, then +vpb and cvt -> bf16
  gemm_nt_big_split<<<dim3(2, 80, 4), dim3(256), 0, stream>>>(video_bf, vpw_bf, vpf, B_ * TV_,
                                                              H_, VD_, VD_ / 4);
  bias_cvt_bf16<<<dim3((B_ * TV_ * H_ / 4 + 255) / 256), dim3(256), 0, stream>>>(
      vpf, vpb, vproj_bf, H_, B_ * TV_ * H_ / 4);

  // 8. xg0 = vproj @ wih0^T + biases
  gemm_nt_big<float><<<dim3(8, 80), dim3(256), 0, stream>>>(
      vproj_bf, (const ushort_t*)(ws + o_wih_std[0]), bih[0], bhh[0], xg, B_ * TV_, G4_, H_);

  // 9. encoder LSTM pair
  lstm_ring<<<dim3(256), dim3(512), 0, stream>>>(
      xg, (const ushort_t*)(ws + o_whhp_hi[0]), (const ushort_t*)(ws + o_whhp_lo[0]),
      (const ushort_t*)(ws + o_whhp_hi[1]), (const ushort_t*)(ws + o_whhp_lo[1]),
      (const ushort_t*)(ws + o_wihp[1]), (const float*)(ws + o_bc[1]), ringA, ringB, hse1, TV_,
      flagA0, flagB0);

  // 10. embedding gather
  gather_embed<<<dim3(TD_, B_), dim3(256), 0, stream>>>(emb_table, captions, emb_bf);

  // 11. Q projection
  gemm_nt_mfma<float><<<dim3(8, TD_), dim3(256), 0, stream>>>(emb_bf, ainw_bf, a_inb, nullptr,
                                                              Qf, B_ * TD_, H_, H_);
  // 12. K + V projections fused
  gemm_kv<<<dim3(8, 80, 2), dim3(256), 0, stream>>>(hse1, ainw_bf, a_inb, Kf, Vf);

  // 13. MHA
  mha_kernel<<<dim3(4, B_), dim3(256), 0, stream>>>(Qf, Kf, Vf, attn_bf);

  // 14. attention out projection
  gemm_nt_mfma<ushort_t><<<dim3(8, TD_), dim3(256), 0, stream>>>(
      attn_bf, aoutw_bf, a_outb, nullptr, attd_bf, B_ * TD_, H_, H_);
  // 15. xg2 = attd @ wih2^T + biases (clobbers Q/K/V overlay — dead)
  gemm_nt_big<float><<<dim3(8, TD_), dim3(256), 0, stream>>>(
      attd_bf, (const ushort_t*)(ws + o_wih_std[2]), bih[2], bhh[2], xg, B_ * TD_, G4_, H_);

  // 16. decoder LSTM pair
  lstm_ring<<<dim3(256), dim3(512), 0, stream>>>(
      xg, (const ushort_t*)(ws + o_whhp_hi[2]), (const ushort_t*)(ws + o_whhp_lo[2]),
      (const ushort_t*)(ws + o_whhp_hi[3]), (const ushort_t*)(ws + o_whhp_lo[3]),
      (const ushort_t*)(ws + o_wihp[3]), (const float*)(ws + o_bc[3]), ringA, ringB, hsd1, TD_,
      flagA1, flagB1);

  // 17. logits: (1216,512) x (10000,512)^T + ob
  gemm_nt_big<float><<<dim3((NV_ + 255) / 256, TD_), dim3(256), 0, stream>>>(
      hsd1, ow_bf, ob, nullptr, out, B_ * TD_, NV_, H_);
}

// Round 13
// 1491.260 us; speedup vs baseline: 1.0270x; 1.0270x over previous
//
#include <hip/hip_runtime.h>
#include <hip/hip_bf16.h>
#include <math.h>

typedef unsigned short ushort_t;
typedef __attribute__((ext_vector_type(8))) short short8;
typedef __attribute__((ext_vector_type(4))) float f32x4;

#define B_ 64
#define TV_ 80
#define TD_ 19
#define H_ 512
#define VD_ 4096
#define NV_ 10000
#define G4_ 2048
#define HN_ 32768  // B_*H_

__device__ __forceinline__ float bf2f(ushort_t u) {
  unsigned int x = ((unsigned int)u) << 16;
  float f;
  __builtin_memcpy(&f, &x, 4);
  return f;
}
__device__ __forceinline__ ushort_t f2bf(float f) {
  unsigned int x;
  __builtin_memcpy(&x, &f, 4);
  x = (x + 0x7FFFu + ((x >> 16) & 1u)) >> 16;
  return (ushort_t)x;
}
__device__ __forceinline__ float sigmoidf_(float x) { return 1.0f / (1.0f + expf(-x)); }
__device__ __forceinline__ short8 zero8() {
  short8 z = {0, 0, 0, 0, 0, 0, 0, 0};
  return z;
}
// fp32 pair -> bf16 fragment (for inline gather)
__device__ __forceinline__ short8 cvt_frag(const float* __restrict__ p) {
  float4 v0 = *reinterpret_cast<const float4*>(p);
  float4 v1 = *reinterpret_cast<const float4*>(p + 4);
  short8 r;
  r[0] = (short)f2bf(v0.x); r[1] = (short)f2bf(v0.y);
  r[2] = (short)f2bf(v0.z); r[3] = (short)f2bf(v0.w);
  r[4] = (short)f2bf(v1.x); r[5] = (short)f2bf(v1.y);
  r[6] = (short)f2bf(v1.z); r[7] = (short)f2bf(v1.w);
  return r;
}
// unpack packed (hi | lo<<16) uints into bf16 fragments via v_perm
__device__ __forceinline__ short8 unpack_hi(uint4 q0, uint4 q1) {
  union { unsigned int u[4]; short8 s; } r;
  r.u[0] = __builtin_amdgcn_perm(q0.y, q0.x, 0x05040100u);
  r.u[1] = __builtin_amdgcn_perm(q0.w, q0.z, 0x05040100u);
  r.u[2] = __builtin_amdgcn_perm(q1.y, q1.x, 0x05040100u);
  r.u[3] = __builtin_amdgcn_perm(q1.w, q1.z, 0x05040100u);
  return r.s;
}
__device__ __forceinline__ short8 unpack_lo(uint4 q0, uint4 q1) {
  union { unsigned int u[4]; short8 s; } r;
  r.u[0] = __builtin_amdgcn_perm(q0.y, q0.x, 0x07060302u);
  r.u[1] = __builtin_amdgcn_perm(q0.w, q0.z, 0x07060302u);
  r.u[2] = __builtin_amdgcn_perm(q1.y, q1.x, 0x07060302u);
  r.u[3] = __builtin_amdgcn_perm(q1.w, q1.z, 0x07060302u);
  return r.s;
}

// ---------------- fp32 -> bf16 convert (video) ----------------
__global__ __launch_bounds__(256) void cvt_f32_bf16(const float* __restrict__ in,
                                                    ushort_t* __restrict__ outp, int n4) {
  int i = blockIdx.x * 256 + threadIdx.x;
  if (i < n4) {
    float4 v = reinterpret_cast<const float4*>(in)[i];
    ushort4 r;
    r.x = f2bf(v.x); r.y = f2bf(v.y); r.z = f2bf(v.z); r.w = f2bf(v.w);
    reinterpret_cast<ushort4*>(outp)[i] = r;
  }
}

// ---------------- fused small-tensor prep: cvts + zero-fills (one dispatch) ----------
__device__ __forceinline__ void cvt_blk(const float* __restrict__ in,
                                        ushort_t* __restrict__ outp, int local, int tid) {
  int i = local * 256 + tid;
  float4 v = reinterpret_cast<const float4*>(in)[i];
  ushort4 r;
  r.x = f2bf(v.x); r.y = f2bf(v.y); r.z = f2bf(v.z); r.w = f2bf(v.w);
  reinterpret_cast<ushort4*>(outp)[i] = r;
}
// ranges: [0,2048) vpw | [2048,3072) wih0 | [3072,4096) wih2 | [4096,4864) ainw
// [4864,5120) aoutw | [5120,10120) ow | [10120,12680) vpf | [12680,12688) flags(32KB)
// [12688,12720) ringA slot0 | [12720,12752) ringB slot0
__global__ __launch_bounds__(256) void prep_small(
    const float* __restrict__ vpw, ushort_t* __restrict__ vpw_bf,
    const float* __restrict__ wih0, ushort_t* __restrict__ wih0_bf,
    const float* __restrict__ wih2, ushort_t* __restrict__ wih2_bf,
    const float* __restrict__ ainw, ushort_t* __restrict__ ainw_bf,
    const float* __restrict__ aoutw, ushort_t* __restrict__ aoutw_bf,
    const float* __restrict__ ow, ushort_t* __restrict__ ow_bf,
    float* __restrict__ vpf, float* __restrict__ flags, float* __restrict__ ringA0,
    float* __restrict__ ringB0) {
  int b = (int)blockIdx.x;
  int tid = (int)threadIdx.x;
  if (b < 2048) { cvt_blk(vpw, vpw_bf, b, tid); return; }
  if (b < 3072) { cvt_blk(wih0, wih0_bf, b - 2048, tid); return; }
  if (b < 4096) { cvt_blk(wih2, wih2_bf, b - 3072, tid); return; }
  if (b < 4864) { cvt_blk(ainw, ainw_bf, b - 4096, tid); return; }
  if (b < 5120) { cvt_blk(aoutw, aoutw_bf, b - 4864, tid); return; }
  if (b < 10120) { cvt_blk(ow, ow_bf, b - 5120, tid); return; }
  float4 z = {0.f, 0.f, 0.f, 0.f};
  if (b < 12680) { reinterpret_cast<float4*>(vpf)[(b - 10120) * 256 + tid] = z; return; }
  if (b < 12688) { reinterpret_cast<float4*>(flags)[(b - 12680) * 256 + tid] = z; return; }
  if (b < 12720) { reinterpret_cast<float4*>(ringA0)[(b - 12688) * 256 + tid] = z; return; }
  reinterpret_cast<float4*>(ringB0)[(b - 12720) * 256 + tid] = z;
}

// ---------------- fused weight prep: whh split x4 | wih permute x2 | bias x2 ----------
// grid (2048, 7), 64 thr. y 0-3: whh layer y; y 4-5: wih layer 1/3; y 6: bias (x<64).
__global__ __launch_bounds__(64) void prep_weights(
    const float* __restrict__ s0, ushort_t* __restrict__ h0, ushort_t* __restrict__ l0,
    const float* __restrict__ s1, ushort_t* __restrict__ h1, ushort_t* __restrict__ l1,
    const float* __restrict__ s2, ushort_t* __restrict__ h2, ushort_t* __restrict__ l2,
    const float* __restrict__ s3, ushort_t* __restrict__ h3, ushort_t* __restrict__ l3,
    const float* __restrict__ wi1, ushort_t* __restrict__ wd1, const float* __restrict__ wi3,
    ushort_t* __restrict__ wd3, const float* __restrict__ bih1, const float* __restrict__ bhh1,
    float* __restrict__ bc1, const float* __restrict__ bih3, const float* __restrict__ bhh3,
    float* __restrict__ bc3) {
  int y = (int)blockIdx.y;
  int p = (int)blockIdx.x;
  int tid = (int)threadIdx.x;
  if (y == 6) {
    if (p >= 64) return;
    int idx = p * 64 + tid;  // 0..4095
    int layer = idx >> 11, q = idx & 2047;
    const float* bih = layer ? bih3 : bih1;
    const float* bhh = layer ? bhh3 : bhh1;
    float* bc = layer ? bc3 : bc1;
    int tile = q >> 4, r = q & 15, gate = r >> 2, sc = r & 3;
    int src = gate * H_ + tile * 4 + sc;
    bc[q] = bih[src] + bhh[src];
    return;
  }
  int tile = p >> 4, r = p & 15, gate = r >> 2, sc = r & 3;
  int i = tid * 8;
  if (y >= 4) {
    const float* src = (y == 4) ? wi1 : wi3;
    ushort_t* hi = (y == 4) ? wd1 : wd3;
    const float* s = src + ((size_t)(gate * H_ + tile * 4 + sc)) * H_;
    float4 v0 = *reinterpret_cast<const float4*>(s + i);
    float4 v1 = *reinterpret_cast<const float4*>(s + i + 4);
    ushort_t* hp = hi + (size_t)p * H_ + i;
    ushort4 rh0, rh1;
    rh0.x = f2bf(v0.x); rh0.y = f2bf(v0.y); rh0.z = f2bf(v0.z); rh0.w = f2bf(v0.w);
    rh1.x = f2bf(v1.x); rh1.y = f2bf(v1.y); rh1.z = f2bf(v1.z); rh1.w = f2bf(v1.w);
    reinterpret_cast<ushort4*>(hp)[0] = rh0;
    reinterpret_cast<ushort4*>(hp)[1] = rh1;
    return;
  }
  const float* src = (y == 0) ? s0 : (y == 1) ? s1 : (y == 2) ? s2 : s3;
  ushort_t* hi = (y == 0) ? h0 : (y == 1) ? h1 : (y == 2) ? h2 : h3;
  ushort_t* lo = (y == 0) ? l0 : (y == 1) ? l1 : (y == 2) ? l2 : l3;
  const float* s = src + ((size_t)(gate * H_ + tile * 4 + sc)) * H_;
  float4 v0 = *reinterpret_cast<const float4*>(s + i);
  float4 v1 = *reinterpret_cast<const float4*>(s + i + 4);
  ushort_t* hp = hi + (size_t)p * H_ + i;
  ushort_t* lp = lo + (size_t)p * H_ + i;
  ushort4 rh0, rl0, rh1, rl1;
  rh0.x = f2bf(v0.x); rl0.x = f2bf(v0.x - bf2f(rh0.x));
  rh0.y = f2bf(v0.y); rl0.y = f2bf(v0.y - bf2f(rh0.y));
  rh0.z = f2bf(v0.z); rl0.z = f2bf(v0.z - bf2f(rh0.z));
  rh0.w = f2bf(v0.w); rl0.w = f2bf(v0.w - bf2f(rh0.w));
  rh1.x = f2bf(v1.x); rl1.x = f2bf(v1.x - bf2f(rh1.x));
  rh1.y = f2bf(v1.y); rl1.y = f2bf(v1.y - bf2f(rh1.y));
  rh1.z = f2bf(v1.z); rl1.z = f2bf(v1.z - bf2f(rh1.z));
  rh1.w = f2bf(v1.w); rl1.w = f2bf(v1.w - bf2f(rh1.w));
  reinterpret_cast<ushort4*>(hp)[0] = rh0;
  reinterpret_cast<ushort4*>(hp)[1] = rh1;
  reinterpret_cast<ushort4*>(lp)[0] = rl0;
  reinterpret_cast<ushort4*>(lp)[1] = rl1;
}

// ---------------- small-tile GEMM (64x64/block) ----------------
__device__ __forceinline__ void store_c(float* C, size_t idx, float v) { C[idx] = v; }
__device__ __forceinline__ void store_c(ushort_t* C, size_t idx, float v) { C[idx] = f2bf(v); }

template <typename OT>
__global__ __launch_bounds__(256) void gemm_nt_mfma(const ushort_t* __restrict__ A,
                                                    const ushort_t* __restrict__ W,
                                                    const float* __restrict__ bias1,
                                                    const float* __restrict__ bias2,
                                                    OT* __restrict__ C, int M, int N, int K) {
  int tid = threadIdx.x;
  int l = tid & 63, w = tid >> 6;
  int wm = w >> 1, wn = w & 1;
  int row0 = blockIdx.y * 64 + wm * 32;
  int col0 = blockIdx.x * 64 + wn * 32;
  int lr = l & 15;
  int kb = (l >> 4) << 3;
  int ar0 = row0 + lr, ar1 = row0 + 16 + lr;
  int wr0 = col0 + lr, wr1 = col0 + 16 + lr;
  bool aok0 = ar0 < M, aok1 = ar1 < M;
  bool wok0 = wr0 < N, wok1 = wr1 < N;
  f32x4 acc00 = {0.f, 0.f, 0.f, 0.f}, acc01 = acc00, acc10 = acc00, acc11 = acc00;
#pragma unroll 2
  for (int k0 = 0; k0 < K; k0 += 32) {
    int k = k0 + kb;
    short8 a0 = aok0 ? *reinterpret_cast<const short8*>(A + (size_t)ar0 * K + k) : zero8();
    short8 a1 = aok1 ? *reinterpret_cast<const short8*>(A + (size_t)ar1 * K + k) : zero8();
    short8 b0 = wok0 ? *reinterpret_cast<const short8*>(W + (size_t)wr0 * K + k) : zero8();
    short8 b1 = wok1 ? *reinterpret_cast<const short8*>(W + (size_t)wr1 * K + k) : zero8();
    acc00 = __builtin_amdgcn_mfma_f32_16x16x32_bf16(a0, b0, acc00, 0, 0, 0);
    acc01 = __builtin_amdgcn_mfma_f32_16x16x32_bf16(a0, b1, acc01, 0, 0, 0);
    acc10 = __builtin_amdgcn_mfma_f32_16x16x32_bf16(a1, b0, acc10, 0, 0, 0);
    acc11 = __builtin_amdgcn_mfma_f32_16x16x32_bf16(a1, b1, acc11, 0, 0, 0);
  }
  int rb = (l >> 4) << 2;
#pragma unroll
  for (int i = 0; i < 2; ++i) {
#pragma unroll
    for (int v = 0; v < 4; ++v) {
      int r = row0 + i * 16 + rb + v;
      if (r < M) {
#pragma unroll
        for (int j = 0; j < 2; ++j) {
          int cc = col0 + j * 16 + lr;
          if (cc < N) {
            float av;
            if (i == 0) av = (j == 0) ? acc00[v] : acc01[v];
            else        av = (j == 0) ? acc10[v] : acc11[v];
            if (bias1) av += bias1[cc];
            if (bias2) av += bias2[cc];
            store_c(C, (size_t)r * N + cc, av);
          }
        }
      }
    }
  }
}

// ---------------- Q/K/V fused projection. z=0: Q with inline embedding gather. --------
__global__ __launch_bounds__(256) void gemm_qkv(const int* __restrict__ cap,
                                                const float* __restrict__ emb_table,
                                                const ushort_t* __restrict__ hse1,
                                                const ushort_t* __restrict__ ainw,
                                                const float* __restrict__ ainb,
                                                float* __restrict__ Qf, float* __restrict__ Kf,
                                                float* __restrict__ Vf) {
  int z = blockIdx.z;
  if (z == 0 && blockIdx.y >= 19) return;
  const ushort_t* W = ainw + (size_t)z * H_ * H_;
  const float* bias = ainb + z * H_;
  float* C = (z == 0) ? Qf : ((z == 1) ? Kf : Vf);
  int tid = threadIdx.x;
  int l = tid & 63, w = tid >> 6;
  int wm = w >> 1, wn = w & 1;
  int row0 = blockIdx.y * 64 + wm * 32;
  int col0 = blockIdx.x * 64 + wn * 32;
  int lr = l & 15;
  int kb = (l >> 4) << 3;
  int ar0 = row0 + lr, ar1 = row0 + 16 + lr;
  const ushort_t* b0p = W + (size_t)(col0 + lr) * H_ + kb;
  const ushort_t* b1p = W + (size_t)(col0 + 16 + lr) * H_ + kb;
  f32x4 acc00 = {0.f, 0.f, 0.f, 0.f}, acc01 = acc00, acc10 = acc00, acc11 = acc00;
  if (z == 0) {
    // gather rows from emb_table (fp32) via caption tokens; convert in-register
    int b0 = ar0 / TD_, t0 = ar0 - b0 * TD_;
    int b1 = ar1 / TD_, t1 = ar1 - b1 * TD_;
    const float* a0base = emb_table + (size_t)cap[b0 * 20 + t0] * H_ + kb;
    const float* a1base = emb_table + (size_t)cap[b1 * 20 + t1] * H_ + kb;
#pragma unroll 2
    for (int k0 = 0; k0 < H_; k0 += 32) {
      short8 a0 = cvt_frag(a0base + k0);
      short8 a1 = cvt_frag(a1base + k0);
      short8 bb0 = *reinterpret_cast<const short8*>(b0p + k0);
      short8 bb1 = *reinterpret_cast<const short8*>(b1p + k0);
      acc00 = __builtin_amdgcn_mfma_f32_16x16x32_bf16(a0, bb0, acc00, 0, 0, 0);
      acc01 = __builtin_amdgcn_mfma_f32_16x16x32_bf16(a0, bb1, acc01, 0, 0, 0);
      acc10 = __builtin_amdgcn_mfma_f32_16x16x32_bf16(a1, bb0, acc10, 0, 0, 0);
      acc11 = __builtin_amdgcn_mfma_f32_16x16x32_bf16(a1, bb1, acc11, 0, 0, 0);
    }
  } else {
    const ushort_t* a0p = hse1 + (size_t)ar0 * H_ + kb;
    const ushort_t* a1p = hse1 + (size_t)ar1 * H_ + kb;
#pragma unroll 2
    for (int k0 = 0; k0 < H_; k0 += 32) {
      short8 a0 = *reinterpret_cast<const short8*>(a0p + k0);
      short8 a1 = *reinterpret_cast<const short8*>(a1p + k0);
      short8 bb0 = *reinterpret_cast<const short8*>(b0p + k0);
      short8 bb1 = *reinterpret_cast<const short8*>(b1p + k0);
      acc00 = __builtin_amdgcn_mfma_f32_16x16x32_bf16(a0, bb0, acc00, 0, 0, 0);
      acc01 = __builtin_amdgcn_mfma_f32_16x16x32_bf16(a0, bb1, acc01, 0, 0, 0);
      acc10 = __builtin_amdgcn_mfma_f32_16x16x32_bf16(a1, bb0, acc10, 0, 0, 0);
      acc11 = __builtin_amdgcn_mfma_f32_16x16x32_bf16(a1, bb1, acc11, 0, 0, 0);
    }
  }
  int rb = (l >> 4) << 2;
#pragma unroll
  for (int i = 0; i < 2; ++i)
#pragma unroll
    for (int v = 0; v < 4; ++v) {
      int r = row0 + i * 16 + rb + v;
#pragma unroll
      for (int j = 0; j < 2; ++j) {
        int cc = col0 + j * 16 + lr;
        float av;
        if (i == 0) av = (j == 0) ? acc00[v] : acc01[v];
        else        av = (j == 0) ? acc10[v] : acc11[v];
        C[(size_t)r * H_ + cc] = av + bias[cc];
      }
    }
}

// ---------------- big-tile GEMM (64 rows x 256 cols / block) ----------------
template <typename OT>
__global__ __launch_bounds__(256) void gemm_nt_big(const ushort_t* __restrict__ A,
                                                   const ushort_t* __restrict__ W,
                                                   const float* __restrict__ bias1,
                                                   const float* __restrict__ bias2,
                                                   OT* __restrict__ C, int M, int N, int K) {
  int tid = threadIdx.x;
  int l = tid & 63, w = tid >> 6;
  int row0 = blockIdx.y * 64;
  int col0 = blockIdx.x * 256 + w * 64;
  int lr = l & 15, kb = (l >> 4) << 3;
  f32x4 acc[4][4];
#pragma unroll
  for (int i = 0; i < 4; ++i)
#pragma unroll
    for (int j = 0; j < 4; ++j) acc[i][j] = (f32x4){0.f, 0.f, 0.f, 0.f};
  const ushort_t* aps[4];
  const ushort_t* wps[4];
  bool wok[4];
#pragma unroll
  for (int fi = 0; fi < 4; ++fi) aps[fi] = A + (size_t)(row0 + fi * 16 + lr) * K + kb;
#pragma unroll
  for (int fj = 0; fj < 4; ++fj) {
    int wr = col0 + fj * 16 + lr;
    wok[fj] = wr < N;
    wps[fj] = W + (size_t)(wok[fj] ? wr : 0) * K + kb;
  }
#pragma unroll 2
  for (int k0 = 0; k0 < K; k0 += 32) {
    short8 af[4], bf[4];
#pragma unroll
    for (int fi = 0; fi < 4; ++fi) af[fi] = *reinterpret_cast<const short8*>(aps[fi] + k0);
#pragma unroll
    for (int fj = 0; fj < 4; ++fj)
      bf[fj] = wok[fj] ? *reinterpret_cast<const short8*>(wps[fj] + k0) : zero8();
#pragma unroll
    for (int fi = 0; fi < 4; ++fi)
#pragma unroll
      for (int fj = 0; fj < 4; ++fj)
        acc[fi][fj] = __builtin_amdgcn_mfma_f32_16x16x32_bf16(af[fi], bf[fj], acc[fi][fj], 0, 0, 0);
  }
  int rb = (l >> 4) << 2;
#pragma unroll
  for (int fi = 0; fi < 4; ++fi) {
#pragma unroll
    for (int v = 0; v < 4; ++v) {
      int r = row0 + fi * 16 + rb + v;
#pragma unroll
      for (int fj = 0; fj < 4; ++fj) {
        int cc = col0 + fj * 16 + lr;
        if (cc < N) {
          float av = acc[fi][fj][v];
          if (bias1) av += bias1[cc];
          if (bias2) av += bias2[cc];
          store_c(C, (size_t)r * N + cc, av);
        }
      }
    }
  }
}

// ---------------- split-K big GEMM with fp32 atomic accumulation ----------------
__global__ __launch_bounds__(256) void gemm_nt_big_split(const ushort_t* __restrict__ A,
                                                         const ushort_t* __restrict__ W,
                                                         float* __restrict__ C, int M, int N,
                                                         int K, int kc) {
  int tid = threadIdx.x;
  int l = tid & 63, w = tid >> 6;
  int row0 = blockIdx.y * 64;
  int col0 = blockIdx.x * 256 + w * 64;
  int lr = l & 15, kb = (l >> 4) << 3;
  int kbeg = blockIdx.z * kc;
  f32x4 acc[4][4];
#pragma unroll
  for (int i = 0; i < 4; ++i)
#pragma unroll
    for (int j = 0; j < 4; ++j) acc[i][j] = (f32x4){0.f, 0.f, 0.f, 0.f};
  const ushort_t* aps[4];
  const ushort_t* wps[4];
#pragma unroll
  for (int fi = 0; fi < 4; ++fi)
    aps[fi] = A + (size_t)(row0 + fi * 16 + lr) * K + kbeg + kb;
#pragma unroll
  for (int fj = 0; fj < 4; ++fj)
    wps[fj] = W + (size_t)(col0 + fj * 16 + lr) * K + kbeg + kb;
#pragma unroll 2
  for (int k0 = 0; k0 < kc; k0 += 32) {
    short8 af[4], bf[4];
#pragma unroll
    for (int fi = 0; fi < 4; ++fi) af[fi] = *reinterpret_cast<const short8*>(aps[fi] + k0);
#pragma unroll
    for (int fj = 0; fj < 4; ++fj) bf[fj] = *reinterpret_cast<const short8*>(wps[fj] + k0);
#pragma unroll
    for (int fi = 0; fi < 4; ++fi)
#pragma unroll
      for (int fj = 0; fj < 4; ++fj)
        acc[fi][fj] = __builtin_amdgcn_mfma_f32_16x16x32_bf16(af[fi], bf[fj], acc[fi][fj], 0, 0, 0);
  }
  int rb = (l >> 4) << 2;
#pragma unroll
  for (int fi = 0; fi < 4; ++fi)
#pragma unroll
    for (int v = 0; v < 4; ++v) {
      int r = row0 + fi * 16 + rb + v;
#pragma unroll
      for (int fj = 0; fj < 4; ++fj) {
        int cc = col0 + fj * 16 + lr;
        atomicAdd(&C[(size_t)r * N + cc], acc[fi][fj][v]);
      }
    }
}

// add column-bias + cvt to bf16 (vproj epilogue)
__global__ __launch_bounds__(256) void bias_cvt_bf16(const float* __restrict__ in,
                                                     const float* __restrict__ bias,
                                                     ushort_t* __restrict__ outp, int ncols,
                                                     int n4) {
  int i = blockIdx.x * 256 + threadIdx.x;
  if (i < n4) {
    float4 v = reinterpret_cast<const float4*>(in)[i];
    int col = (i * 4) & (ncols - 1);
    float4 bv = *reinterpret_cast<const float4*>(bias + col);
    ushort4 r;
    r.x = f2bf(v.x + bv.x); r.y = f2bf(v.y + bv.y);
    r.z = f2bf(v.z + bv.z); r.w = f2bf(v.w + bv.w);
    reinterpret_cast<ushort4*>(outp)[i] = r;
  }
}

// ---------------- epoch-flag wait: wave 0 polls 128 spread flags (PROVEN R11) ----------
__device__ __forceinline__ void wait_flags2(const int* __restrict__ fA, int tA,
                                            const int* __restrict__ fB, int tB, int tid) {
  if (tid < 64) {
    for (;;) {
      int a0 = __hip_atomic_load(fA + tid * 16, __ATOMIC_RELAXED, __HIP_MEMORY_SCOPE_AGENT);
      int a1 = __hip_atomic_load(fA + (tid + 64) * 16, __ATOMIC_RELAXED, __HIP_MEMORY_SCOPE_AGENT);
      bool ok = (a0 >= tA) && (a1 >= tA);
      if (fB) {
        int b0 = __hip_atomic_load(fB + tid * 16, __ATOMIC_RELAXED, __HIP_MEMORY_SCOPE_AGENT);
        int b1 = __hip_atomic_load(fB + (tid + 64) * 16, __ATOMIC_RELAXED, __HIP_MEMORY_SCOPE_AGENT);
        ok = ok && (b0 >= tB) && (b1 >= tB);
      }
      if (__all(ok)) break;
      __builtin_amdgcn_s_sleep(2);
    }
  }
  __syncthreads();
}

// ---------------- persistent diagonal LSTM pair (R11 PROVEN: 890 us encoder) -----------
__global__ __launch_bounds__(512, 2) void lstm_ring(
    const float* __restrict__ xg, const ushort_t* __restrict__ whhA_hi,
    const ushort_t* __restrict__ whhA_lo, const ushort_t* __restrict__ whhB_hi,
    const ushort_t* __restrict__ whhB_lo, const ushort_t* __restrict__ wihB,
    const float* __restrict__ bcB, unsigned int* __restrict__ ringA,
    unsigned int* __restrict__ ringB, ushort_t* __restrict__ hsB, int T,
    int* __restrict__ flagA, int* __restrict__ flagB) {
  __shared__ float gbuf[2][64][17];
  const int role = (int)(blockIdx.x >> 7);  // 0 = layer A, 1 = layer B
  const int tile = (int)(blockIdx.x & 127);
  const int tid = (int)threadIdx.x;
  const int g2 = tid >> 8;                 // K-half
  const int u = tid & 255;
  const int l = u & 63, w = u >> 6;
  const int lr = l & 15, kq = l >> 4;
  const int kb = g2 * 256 + (kq << 3);     // K element offset
  const int arow = (w << 4) + lr;
  const int prow = tile * 16 + lr;
  const int row = tid >> 2, s = tid & 3;   // gate phase (tid<256)
  const int col = (tile << 2) + s;
  unsigned int* ring_own = role ? ringB : ringA;
  int* flag_own = (role ? flagB : flagA) + tile * 16;

  short8 wb[8], wbl[8];
  {
    const ushort_t* bp = (role ? whhB_hi : whhA_hi) + (size_t)prow * H_ + kb;
    const ushort_t* blp = (role ? whhB_lo : whhA_lo) + (size_t)prow * H_ + kb;
#pragma unroll
    for (int i = 0; i < 8; ++i) {
      wb[i] = *reinterpret_cast<const short8*>(bp + i * 32);
      wbl[i] = *reinterpret_cast<const short8*>(blp + i * 32);
    }
  }
  const ushort_t* wpp = wihB + (size_t)prow * H_ + kb;
  float bci = 0.f, bcf = 0.f, bcg = 0.f, bco = 0.f;
  if (role && tid < 256) {
    bci = bcB[tile * 16 + 0 + s];
    bcf = bcB[tile * 16 + 4 + s];
    bcg = bcB[tile * 16 + 8 + s];
    bco = bcB[tile * 16 + 12 + s];
  }
  float creg = 0.f;
  for (int t = 0; t < T; ++t) {
    float xgi = 0.f, xgf = 0.f, xgg = 0.f, xgo = 0.f;
    if (!role && tid < 256) {
      size_t xb = ((size_t)row * T + t) * (size_t)G4_ + col;
      xgi = xg[xb]; xgf = xg[xb + 512]; xgg = xg[xb + 1024]; xgo = xg[xb + 1536];
    }
    if (role == 0) {
      if (t > 0) wait_flags2(flagA, t, nullptr, 0, tid);
      else __syncthreads();
    } else {
      wait_flags2(flagA, t + 1, (t > 0) ? flagB : nullptr, t, tid);
    }
    const unsigned int* rh = ring_own + (size_t)t * HN_ + (size_t)arow * H_ + kb;
    f32x4 a0 = {0.f, 0.f, 0.f, 0.f}, a1 = a0, a2 = a0, a3 = a0;
    if (role == 0) {
      uint4 q[16];
#pragma unroll
      for (int i = 0; i < 8; ++i) {
        q[2 * i] = *reinterpret_cast<const uint4*>(rh + i * 32);
        q[2 * i + 1] = *reinterpret_cast<const uint4*>(rh + i * 32 + 4);
      }
#pragma unroll
      for (int i = 0; i < 8; ++i) {
        short8 a = unpack_hi(q[2 * i], q[2 * i + 1]);
        short8 al = unpack_lo(q[2 * i], q[2 * i + 1]);
        a0 = __builtin_amdgcn_mfma_f32_16x16x32_bf16(a, wb[i], a0, 0, 0, 0);
        a1 = __builtin_amdgcn_mfma_f32_16x16x32_bf16(al, wb[i], a1, 0, 0, 0);
        a2 = __builtin_amdgcn_mfma_f32_16x16x32_bf16(a, wbl[i], a2, 0, 0, 0);
      }
    } else {
      const unsigned int* rx = ringA + (size_t)(t + 1) * HN_ + (size_t)arow * H_ + kb;
      uint4 q[16], p[16];
#pragma unroll
      for (int i = 0; i < 8; ++i) {
        q[2 * i] = *reinterpret_cast<const uint4*>(rh + i * 32);
        q[2 * i + 1] = *reinterpret_cast<const uint4*>(rh + i * 32 + 4);
      }
#pragma unroll
      for (int i = 0; i < 8; ++i) {
        p[2 * i] = *reinterpret_cast<const uint4*>(rx + i * 32);
        p[2 * i + 1] = *reinterpret_cast<const uint4*>(rx + i * 32 + 4);
      }
#pragma unroll
      for (int i = 0; i < 8; ++i) {
        short8 a = unpack_hi(q[2 * i], q[2 * i + 1]);
        short8 al = unpack_lo(q[2 * i], q[2 * i + 1]);
        short8 x = unpack_hi(p[2 * i], p[2 * i + 1]);
        short8 wx = *reinterpret_cast<const short8*>(wpp + i * 32);
        a0 = __builtin_amdgcn_mfma_f32_16x16x32_bf16(a, wb[i], a0, 0, 0, 0);
        a1 = __builtin_amdgcn_mfma_f32_16x16x32_bf16(al, wb[i], a1, 0, 0, 0);
        a2 = __builtin_amdgcn_mfma_f32_16x16x32_bf16(a, wbl[i], a2, 0, 0, 0);
        a3 = __builtin_amdgcn_mfma_f32_16x16x32_bf16(x, wx, a3, 0, 0, 0);
      }
    }
    f32x4 acc = (a0 + a1) + (a2 + a3);
    const int rb = (w << 4) + (kq << 2);
#pragma unroll
    for (int v = 0; v < 4; ++v) gbuf[g2][rb + v][lr] = acc[v];
    __syncthreads();
    if (tid < 256) {
      float gi = gbuf[0][row][0 + s] + gbuf[1][row][0 + s];
      float gf = gbuf[0][row][4 + s] + gbuf[1][row][4 + s];
      float gg = gbuf[0][row][8 + s] + gbuf[1][row][8 + s];
      float go = gbuf[0][row][12 + s] + gbuf[1][row][12 + s];
      if (role) {
        gi += bci; gf += bcf; gg += bcg; go += bco;
      } else {
        gi += xgi; gf += xgf; gg += xgg; go += xgo;
      }
      float cv = sigmoidf_(gf) * creg + sigmoidf_(gi) * tanhf(gg);
      float hv = sigmoidf_(go) * tanhf(cv);
      creg = cv;
      ushort_t hh = f2bf(hv);
      ushort_t hl = f2bf(hv - bf2f(hh));
      unsigned int pk = (unsigned int)hh | ((unsigned int)hl << 16);
      __hip_atomic_store(ring_own + (size_t)(t + 1) * HN_ + (size_t)row * H_ + col, pk,
                         __ATOMIC_RELAXED, __HIP_MEMORY_SCOPE_AGENT);
      if (role) hsB[((size_t)row * T + t) * H_ + col] = hh;
    }
    __syncthreads();  // vmcnt(0) drain of all waves' write-through stores, then barrier
    if (tid == 0)
      __hip_atomic_store(flag_own, t + 1, __ATOMIC_RELAXED, __HIP_MEMORY_SCOPE_AGENT);
  }
}

// ---------------- MHA (fp32) ----------------
__global__ __launch_bounds__(256) void mha_kernel(const float* __restrict__ Qf,
                                                  const float* __restrict__ Kf,
                                                  const float* __restrict__ Vf,
                                                  ushort_t* __restrict__ attnout) {
  __shared__ float Qs[19][132];
  __shared__ float Ks[80][132];
  __shared__ float Ss[19][80];
  int h = blockIdx.x, b = blockIdx.y;
  int tid = threadIdx.x;
  for (int idx = tid; idx < 19 * 128; idx += 256) {
    int q = idx >> 7, d = idx & 127;
    Qs[q][d] = Qf[((size_t)(b * TD_ + q)) * H_ + h * 128 + d];
  }
  for (int idx = tid; idx < 80 * 128; idx += 256) {
    int k = idx >> 7, d = idx & 127;
    Ks[k][d] = Kf[((size_t)(b * TV_ + k)) * H_ + h * 128 + d];
  }
  __syncthreads();
  for (int u = tid; u < 240; u += 256) {
    int k = u / 3, qo = u % 3;
    int q0 = qo * 8;
    int nq = (qo == 2) ? 3 : 8;
    float s[8] = {0.f, 0.f, 0.f, 0.f, 0.f, 0.f, 0.f, 0.f};
    for (int d = 0; d < 128; d += 4) {
      float4 kv = *reinterpret_cast<const float4*>(&Ks[k][d]);
#pragma unroll
      for (int qi = 0; qi < 8; ++qi) {
        if (qi < nq) {
          float4 qv = *reinterpret_cast<const float4*>(&Qs[q0 + qi][d]);
          s[qi] += qv.x * kv.x + qv.y * kv.y + qv.z * kv.z + qv.w * kv.w;
        }
      }
    }
    for (int qi = 0; qi < nq; ++qi) Ss[q0 + qi][k] = s[qi] * 0.08838834764831845f;
  }
  __syncthreads();
  if (tid < 19) {
    float m = -1e30f;
    for (int k = 0; k < 80; ++k) m = fmaxf(m, Ss[tid][k]);
    float sum = 0.f;
    for (int k = 0; k < 80; ++k) {
      float e = expf(Ss[tid][k] - m);
      Ss[tid][k] = e;
      sum += e;
    }
    float inv = 1.0f / sum;
    for (int k = 0; k < 80; ++k) Ss[tid][k] *= inv;
  }
  __syncthreads();
  for (int u = tid; u < 160; u += 256) {
    int qp = u / 16, d0 = (u % 16) * 8;
    int q0 = qp * 2;
    int nq = (q0 + 1 < 19) ? 2 : 1;
    float o0[8] = {0.f, 0.f, 0.f, 0.f, 0.f, 0.f, 0.f, 0.f};
    float o1[8] = {0.f, 0.f, 0.f, 0.f, 0.f, 0.f, 0.f, 0.f};
#pragma unroll 4
    for (int k = 0; k < 80; ++k) {
      const float* vp = Vf + ((size_t)(b * TV_ + k)) * H_ + h * 128 + d0;
      float4 v0 = *reinterpret_cast<const float4*>(vp);
      float4 v1 = *reinterpret_cast<const float4*>(vp + 4);
      float p0 = Ss[q0][k];
      o0[0] += p0 * v0.x; o0[1] += p0 * v0.y; o0[2] += p0 * v0.z; o0[3] += p0 * v0.w;
      o0[4] += p0 * v1.x; o0[5] += p0 * v1.y; o0[6] += p0 * v1.z; o0[7] += p0 * v1.w;
      if (nq == 2) {
        float p1 = Ss[q0 + 1][k];
        o1[0] += p1 * v0.x; o1[1] += p1 * v0.y; o1[2] += p1 * v0.z; o1[3] += p1 * v0.w;
        o1[4] += p1 * v1.x; o1[5] += p1 * v1.y; o1[6] += p1 * v1.z; o1[7] += p1 * v1.w;
      }
    }
    for (int j = 0; j < 8; ++j)
      attnout[((size_t)(b * TD_ + q0)) * H_ + h * 128 + d0 + j] = f2bf(o0[j]);
    if (nq == 2)
      for (int j = 0; j < 8; ++j)
        attnout[((size_t)(b * TD_ + q0 + 1)) * H_ + h * 128 + d0 + j] = f2bf(o1[j]);
  }
}

// ---------------- host ----------------
extern "C" void kernel_launch(void* const* d_in, const int* in_sizes, int n_in, void* d_out,
                              int out_size, void* d_ws, size_t ws_size, hipStream_t stream) {
  const float* video = (const float*)d_in[0];
  const int* captions = (const int*)d_in[1];
  const float* vpw = (const float*)d_in[2];
  const float* vpb = (const float*)d_in[3];
  const float* emb_table = (const float*)d_in[4];
  const float* wih[4] = {(const float*)d_in[5], (const float*)d_in[9], (const float*)d_in[13],
                         (const float*)d_in[17]};
  const float* whh[4] = {(const float*)d_in[6], (const float*)d_in[10], (const float*)d_in[14],
                         (const float*)d_in[18]};
  const float* bih[4] = {(const float*)d_in[7], (const float*)d_in[11], (const float*)d_in[15],
                         (const float*)d_in[19]};
  const float* bhh[4] = {(const float*)d_in[8], (const float*)d_in[12], (const float*)d_in[16],
                         (const float*)d_in[20]};
  const float* a_inw = (const float*)d_in[21];
  const float* a_inb = (const float*)d_in[22];
  const float* a_outw = (const float*)d_in[23];
  const float* a_outb = (const float*)d_in[24];
  const float* ow = (const float*)d_in[25];
  const float* ob = (const float*)d_in[26];
  float* out = (float*)d_out;

  char* ws = (char*)d_ws;
  size_t o = 0;
  auto take = [&](size_t bytes) {
    size_t cur = o;
    o += (bytes + 255) & ~(size_t)255;
    return cur;
  };
  const size_t o_vpw = take((size_t)H_ * VD_ * 2);
  size_t o_wih_std[4], o_whhp_hi[4], o_whhp_lo[4], o_wihp[4], o_bc[4];
  for (int i = 0; i < 4; ++i) {
    o_wih_std[i] = (i == 0 || i == 2) ? take((size_t)G4_ * H_ * 2) : 0;
    o_whhp_hi[i] = take((size_t)G4_ * H_ * 2);
    o_whhp_lo[i] = take((size_t)G4_ * H_ * 2);
    o_wihp[i] = (i == 1 || i == 3) ? take((size_t)G4_ * H_ * 2) : 0;
    o_bc[i] = (i == 1 || i == 3) ? take((size_t)G4_ * 4) : 0;
  }
  const size_t o_ainw = take((size_t)3 * H_ * H_ * 2);
  const size_t o_aoutw = take((size_t)H_ * H_ * 2);
  const size_t o_ow = take((size_t)NV_ * H_ * 2);
  const size_t o_vproj = take((size_t)B_ * TV_ * H_ * 2);
  const size_t o_xg = take((size_t)B_ * TV_ * G4_ * 4);  // video_bf overlay, then xg, then Q/K/V
  const size_t o_hse1 = take((size_t)B_ * TV_ * H_ * 2);
  const size_t o_attn = take((size_t)B_ * TD_ * H_ * 2);
  const size_t o_attd = take((size_t)B_ * TD_ * H_ * 2);
  const size_t o_hsd1 = take((size_t)B_ * TD_ * H_ * 2);
  const size_t o_flags = take(4 * 128 * 64);  // 4 epoch-flag arrays, 64B stride (32KB)
  const size_t o_vpf = take((size_t)B_ * TV_ * H_ * 4);  // vproj fp32 accum
  const size_t o_ringA = take((size_t)(TV_ + 1) * HN_ * 4);
  const size_t o_ringB = take((size_t)(TV_ + 1) * HN_ * 4);

  ushort_t* vpw_bf = (ushort_t*)(ws + o_vpw);
  ushort_t* ainw_bf = (ushort_t*)(ws + o_ainw);
  ushort_t* aoutw_bf = (ushort_t*)(ws + o_aoutw);
  ushort_t* ow_bf = (ushort_t*)(ws + o_ow);
  ushort_t* vproj_bf = (ushort_t*)(ws + o_vproj);
  float* xg = (float*)(ws + o_xg);
  ushort_t* video_bf = (ushort_t*)(ws + o_xg);  // overlay
  ushort_t* hse1 = (ushort_t*)(ws + o_hse1);
  ushort_t* attn_bf = (ushort_t*)(ws + o_attn);
  ushort_t* attd_bf = (ushort_t*)(ws + o_attd);
  ushort_t* hsd1 = (ushort_t*)(ws + o_hsd1);
  float* Qf = (float*)(ws + o_xg);
  float* Kf = (float*)(ws + o_xg + 2490368);
  float* Vf = (float*)(ws + o_xg + 2490368 + 10485760);
  int* flagA0 = (int*)(ws + o_flags);
  int* flagB0 = flagA0 + 2048;
  int* flagA1 = flagA0 + 4096;
  int* flagB1 = flagA0 + 6144;
  float* vpf = (float*)(ws + o_vpf);
  unsigned int* ringA = (unsigned int*)(ws + o_ringA);
  unsigned int* ringB = (unsigned int*)(ws + o_ringB);

  // 1. video cvt
  cvt_f32_bf16<<<dim3(20480), dim3(256), 0, stream>>>(video, video_bf,
                                                      (int)((size_t)B_ * TV_ * VD_ / 4));
  // 2. fused small cvts + zero-fills
  prep_small<<<dim3(12752), dim3(256), 0, stream>>>(
      vpw, vpw_bf, wih[0], (ushort_t*)(ws + o_wih_std[0]), wih[2],
      (ushort_t*)(ws + o_wih_std[2]), a_inw, ainw_bf, a_outw, aoutw_bf, ow, ow_bf, vpf,
      (float*)(ws + o_flags), (float*)ringA, (float*)ringB);
  // 3. fused weight permutes (whh x4 | wih x2 | bias x2)
  prep_weights<<<dim3(G4_, 7), dim3(64), 0, stream>>>(
      whh[0], (ushort_t*)(ws + o_whhp_hi[0]), (ushort_t*)(ws + o_whhp_lo[0]), whh[1],
      (ushort_t*)(ws + o_whhp_hi[1]), (ushort_t*)(ws + o_whhp_lo[1]), whh[2],
      (ushort_t*)(ws + o_whhp_hi[2]), (ushort_t*)(ws + o_whhp_lo[2]), whh[3],
      (ushort_t*)(ws + o_whhp_hi[3]), (ushort_t*)(ws + o_whhp_lo[3]), wih[1],
      (ushort_t*)(ws + o_wihp[1]), wih[3], (ushort_t*)(ws + o_wihp[3]), bih[1], bhh[1],
      (float*)(ws + o_bc[1]), bih[3], bhh[3], (float*)(ws + o_bc[3]));

  // 4-5. vproj: split-K x4 atomic fp32, then +vpb and cvt -> bf16
  gemm_nt_big_split<<<dim3(2, 80, 4), dim3(256), 0, stream>>>(video_bf, vpw_bf, vpf, B_ * TV_,
                                                              H_, VD_, VD_ / 4);
  bias_cvt_bf16<<<dim3((B_ * TV_ * H_ / 4 + 255) / 256), dim3(256), 0, stream>>>(
      vpf, vpb, vproj_bf, H_, B_ * TV_ * H_ / 4);

  // 6. xg0 = vproj @ wih0^T + biases
  gemm_nt_big<float><<<dim3(8, 80), dim3(256), 0, stream>>>(
      vproj_bf, (const ushort_t*)(ws + o_wih_std[0]), bih[0], bhh[0], xg, B_ * TV_, G4_, H_);

  // 7. encoder LSTM pair
  lstm_ring<<<dim3(256), dim3(512), 0, stream>>>(
      xg, (const ushort_t*)(ws + o_whhp_hi[0]), (const ushort_t*)(ws + o_whhp_lo[0]),
      (const ushort_t*)(ws + o_whhp_hi[1]), (const ushort_t*)(ws + o_whhp_lo[1]),
      (const ushort_t*)(ws + o_wihp[1]), (const float*)(ws + o_bc[1]), ringA, ringB, hse1, TV_,
      flagA0, flagB0);

  // 8. Q (inline embedding gather) + K + V in one dispatch
  gemm_qkv<<<dim3(8, 80, 3), dim3(256), 0, stream>>>(captions, emb_table, hse1, ainw_bf, a_inb,
                                                     Qf, Kf, Vf);

  // 9. MHA
  mha_kernel<<<dim3(4, B_), dim3(256), 0, stream>>>(Qf, Kf, Vf, attn_bf);

  // 10. attention out projection
  gemm_nt_mfma<ushort_t><<<dim3(8, TD_), dim3(256), 0, stream>>>(
      attn_bf, aoutw_bf, a_outb, nullptr, attd_bf, B_ * TD_, H_, H_);
  // 11. xg2 = attd @ wih2^T + biases (clobbers Q/K/V overlay — dead)
  gemm_nt_big<float><<<dim3(8, TD_), dim3(256), 0, stream>>>(
      attd_bf, (const ushort_t*)(ws + o_wih_std[2]), bih[2], bhh[2], xg, B_ * TD_, G4_, H_);

  // 12. decoder LSTM pair
  lstm_ring<<<dim3(256), dim3(512), 0, stream>>>(
      xg, (const ushort_t*)(ws + o_whhp_hi[2]), (const ushort_t*)(ws + o_whhp_lo[2]),
      (const ushort_t*)(ws + o_whhp_hi[3]), (const ushort_t*)(ws + o_whhp_lo[3]),
      (const ushort_t*)(ws + o_wihp[3]), (const float*)(ws + o_bc[3]), ringA, ringB, hsd1, TD_,
      flagA1, flagB1);

  // 13. logits: (1216,512) x (10000,512)^T + ob
  gemm_nt_big<float><<<dim3((NV_ + 255) / 256, TD_), dim3(256), 0, stream>>>(
      hsd1, ow_bf, ob, nullptr, out, B_ * TD_, NV_, H_);
}

// Round 14
// 1314.307 us; speedup vs baseline: 1.1653x; 1.1346x over previous
//
#include <hip/hip_runtime.h>
#include <hip/hip_bf16.h>
#include <math.h>

typedef unsigned short ushort_t;
typedef __attribute__((ext_vector_type(8))) short short8;
typedef __attribute__((ext_vector_type(4))) float f32x4;

#define B_ 64
#define TV_ 80
#define TD_ 19
#define H_ 512
#define VD_ 4096
#define NV_ 10000
#define G4_ 2048
#define HN_ 32768   // B_*H_ (uints per packed ring slot)
#define XN_ 16384   // B_*H_/2 (uints per hi-only ring slot)

__device__ __forceinline__ float bf2f(ushort_t u) {
  unsigned int x = ((unsigned int)u) << 16;
  float f;
  __builtin_memcpy(&f, &x, 4);
  return f;
}
__device__ __forceinline__ ushort_t f2bf(float f) {
  unsigned int x;
  __builtin_memcpy(&x, &f, 4);
  x = (x + 0x7FFFu + ((x >> 16) & 1u)) >> 16;
  return (ushort_t)x;
}
__device__ __forceinline__ float sigmoidf_(float x) { return 1.0f / (1.0f + expf(-x)); }
__device__ __forceinline__ short8 zero8() {
  short8 z = {0, 0, 0, 0, 0, 0, 0, 0};
  return z;
}
// fp32 pair -> bf16 fragment (for inline gather)
__device__ __forceinline__ short8 cvt_frag(const float* __restrict__ p) {
  float4 v0 = *reinterpret_cast<const float4*>(p);
  float4 v1 = *reinterpret_cast<const float4*>(p + 4);
  short8 r;
  r[0] = (short)f2bf(v0.x); r[1] = (short)f2bf(v0.y);
  r[2] = (short)f2bf(v0.z); r[3] = (short)f2bf(v0.w);
  r[4] = (short)f2bf(v1.x); r[5] = (short)f2bf(v1.y);
  r[6] = (short)f2bf(v1.z); r[7] = (short)f2bf(v1.w);
  return r;
}
// unpack packed (hi | lo<<16) uints into bf16 fragments via v_perm
__device__ __forceinline__ short8 unpack_hi(uint4 q0, uint4 q1) {
  union { unsigned int u[4]; short8 s; } r;
  r.u[0] = __builtin_amdgcn_perm(q0.y, q0.x, 0x05040100u);
  r.u[1] = __builtin_amdgcn_perm(q0.w, q0.z, 0x05040100u);
  r.u[2] = __builtin_amdgcn_perm(q1.y, q1.x, 0x05040100u);
  r.u[3] = __builtin_amdgcn_perm(q1.w, q1.z, 0x05040100u);
  return r.s;
}
__device__ __forceinline__ short8 unpack_lo(uint4 q0, uint4 q1) {
  union { unsigned int u[4]; short8 s; } r;
  r.u[0] = __builtin_amdgcn_perm(q0.y, q0.x, 0x07060302u);
  r.u[1] = __builtin_amdgcn_perm(q0.w, q0.z, 0x07060302u);
  r.u[2] = __builtin_amdgcn_perm(q1.y, q1.x, 0x07060302u);
  r.u[3] = __builtin_amdgcn_perm(q1.w, q1.z, 0x07060302u);
  return r.s;
}

// ---------------- fp32 -> bf16 convert (video) ----------------
__global__ __launch_bounds__(256) void cvt_f32_bf16(const float* __restrict__ in,
                                                    ushort_t* __restrict__ outp, int n4) {
  int i = blockIdx.x * 256 + threadIdx.x;
  if (i < n4) {
    float4 v = reinterpret_cast<const float4*>(in)[i];
    ushort4 r;
    r.x = f2bf(v.x); r.y = f2bf(v.y); r.z = f2bf(v.z); r.w = f2bf(v.w);
    reinterpret_cast<ushort4*>(outp)[i] = r;
  }
}

// ---------------- fused small-tensor prep: cvts + zero-fills (one dispatch) ----------
__device__ __forceinline__ void cvt_blk(const float* __restrict__ in,
                                        ushort_t* __restrict__ outp, int local, int tid) {
  int i = local * 256 + tid;
  float4 v = reinterpret_cast<const float4*>(in)[i];
  ushort4 r;
  r.x = f2bf(v.x); r.y = f2bf(v.y); r.z = f2bf(v.z); r.w = f2bf(v.w);
  reinterpret_cast<ushort4*>(outp)[i] = r;
}
// ranges: [0,2048) vpw | [2048,3072) wih0 | [3072,4096) wih2 | [4096,4864) ainw
// [4864,5120) aoutw | [5120,10120) ow | [10120,12680) vpf | [12680,12688) flags(32KB)
// [12688,12720) ringA slot0 | [12720,12752) ringB slot0 | [12752,12768) ringX slot0
__global__ __launch_bounds__(256) void prep_small(
    const float* __restrict__ vpw, ushort_t* __restrict__ vpw_bf,
    const float* __restrict__ wih0, ushort_t* __restrict__ wih0_bf,
    const float* __restrict__ wih2, ushort_t* __restrict__ wih2_bf,
    const float* __restrict__ ainw, ushort_t* __restrict__ ainw_bf,
    const float* __restrict__ aoutw, ushort_t* __restrict__ aoutw_bf,
    const float* __restrict__ ow, ushort_t* __restrict__ ow_bf,
    float* __restrict__ vpf, float* __restrict__ flags, float* __restrict__ ringA0,
    float* __restrict__ ringB0, float* __restrict__ ringX0) {
  int b = (int)blockIdx.x;
  int tid = (int)threadIdx.x;
  if (b < 2048) { cvt_blk(vpw, vpw_bf, b, tid); return; }
  if (b < 3072) { cvt_blk(wih0, wih0_bf, b - 2048, tid); return; }
  if (b < 4096) { cvt_blk(wih2, wih2_bf, b - 3072, tid); return; }
  if (b < 4864) { cvt_blk(ainw, ainw_bf, b - 4096, tid); return; }
  if (b < 5120) { cvt_blk(aoutw, aoutw_bf, b - 4864, tid); return; }
  if (b < 10120) { cvt_blk(ow, ow_bf, b - 5120, tid); return; }
  float4 z = {0.f, 0.f, 0.f, 0.f};
  if (b < 12680) { reinterpret_cast<float4*>(vpf)[(b - 10120) * 256 + tid] = z; return; }
  if (b < 12688) { reinterpret_cast<float4*>(flags)[(b - 12680) * 256 + tid] = z; return; }
  if (b < 12720) { reinterpret_cast<float4*>(ringA0)[(b - 12688) * 256 + tid] = z; return; }
  if (b < 12752) { reinterpret_cast<float4*>(ringB0)[(b - 12720) * 256 + tid] = z; return; }
  reinterpret_cast<float4*>(ringX0)[(b - 12752) * 256 + tid] = z;
}

// ---------------- fused weight prep: whh split x4 | wih permute x2 | bias x2 ----------
// grid (2048, 7), 64 thr. y 0-3: whh layer y; y 4-5: wih layer 1/3; y 6: bias (x<64).
__global__ __launch_bounds__(64) void prep_weights(
    const float* __restrict__ s0, ushort_t* __restrict__ h0, ushort_t* __restrict__ l0,
    const float* __restrict__ s1, ushort_t* __restrict__ h1, ushort_t* __restrict__ l1,
    const float* __restrict__ s2, ushort_t* __restrict__ h2, ushort_t* __restrict__ l2,
    const float* __restrict__ s3, ushort_t* __restrict__ h3, ushort_t* __restrict__ l3,
    const float* __restrict__ wi1, ushort_t* __restrict__ wd1, const float* __restrict__ wi3,
    ushort_t* __restrict__ wd3, const float* __restrict__ bih1, const float* __restrict__ bhh1,
    float* __restrict__ bc1, const float* __restrict__ bih3, const float* __restrict__ bhh3,
    float* __restrict__ bc3) {
  int y = (int)blockIdx.y;
  int p = (int)blockIdx.x;
  int tid = (int)threadIdx.x;
  if (y == 6) {
    if (p >= 64) return;
    int idx = p * 64 + tid;  // 0..4095
    int layer = idx >> 11, q = idx & 2047;
    const float* bih = layer ? bih3 : bih1;
    const float* bhh = layer ? bhh3 : bhh1;
    float* bc = layer ? bc3 : bc1;
    int tile = q >> 4, r = q & 15, gate = r >> 2, sc = r & 3;
    int src = gate * H_ + tile * 4 + sc;
    bc[q] = bih[src] + bhh[src];
    return;
  }
  int tile = p >> 4, r = p & 15, gate = r >> 2, sc = r & 3;
  int i = tid * 8;
  if (y >= 4) {
    const float* src = (y == 4) ? wi1 : wi3;
    ushort_t* hi = (y == 4) ? wd1 : wd3;
    const float* s = src + ((size_t)(gate * H_ + tile * 4 + sc)) * H_;
    float4 v0 = *reinterpret_cast<const float4*>(s + i);
    float4 v1 = *reinterpret_cast<const float4*>(s + i + 4);
    ushort_t* hp = hi + (size_t)p * H_ + i;
    ushort4 rh0, rh1;
    rh0.x = f2bf(v0.x); rh0.y = f2bf(v0.y); rh0.z = f2bf(v0.z); rh0.w = f2bf(v0.w);
    rh1.x = f2bf(v1.x); rh1.y = f2bf(v1.y); rh1.z = f2bf(v1.z); rh1.w = f2bf(v1.w);
    reinterpret_cast<ushort4*>(hp)[0] = rh0;
    reinterpret_cast<ushort4*>(hp)[1] = rh1;
    return;
  }
  const float* src = (y == 0) ? s0 : (y == 1) ? s1 : (y == 2) ? s2 : s3;
  ushort_t* hi = (y == 0) ? h0 : (y == 1) ? h1 : (y == 2) ? h2 : h3;
  ushort_t* lo = (y == 0) ? l0 : (y == 1) ? l1 : (y == 2) ? l2 : l3;
  const float* s = src + ((size_t)(gate * H_ + tile * 4 + sc)) * H_;
  float4 v0 = *reinterpret_cast<const float4*>(s + i);
  float4 v1 = *reinterpret_cast<const float4*>(s + i + 4);
  ushort_t* hp = hi + (size_t)p * H_ + i;
  ushort_t* lp = lo + (size_t)p * H_ + i;
  ushort4 rh0, rl0, rh1, rl1;
  rh0.x = f2bf(v0.x); rl0.x = f2bf(v0.x - bf2f(rh0.x));
  rh0.y = f2bf(v0.y); rl0.y = f2bf(v0.y - bf2f(rh0.y));
  rh0.z = f2bf(v0.z); rl0.z = f2bf(v0.z - bf2f(rh0.z));
  rh0.w = f2bf(v0.w); rl0.w = f2bf(v0.w - bf2f(rh0.w));
  rh1.x = f2bf(v1.x); rl1.x = f2bf(v1.x - bf2f(rh1.x));
  rh1.y = f2bf(v1.y); rl1.y = f2bf(v1.y - bf2f(rh1.y));
  rh1.z = f2bf(v1.z); rl1.z = f2bf(v1.z - bf2f(rh1.z));
  rh1.w = f2bf(v1.w); rl1.w = f2bf(v1.w - bf2f(rh1.w));
  reinterpret_cast<ushort4*>(hp)[0] = rh0;
  reinterpret_cast<ushort4*>(hp)[1] = rh1;
  reinterpret_cast<ushort4*>(lp)[0] = rl0;
  reinterpret_cast<ushort4*>(lp)[1] = rl1;
}

// ---------------- small-tile GEMM (64x64/block) ----------------
__device__ __forceinline__ void store_c(float* C, size_t idx, float v) { C[idx] = v; }
__device__ __forceinline__ void store_c(ushort_t* C, size_t idx, float v) { C[idx] = f2bf(v); }

template <typename OT>
__global__ __launch_bounds__(256) void gemm_nt_mfma(const ushort_t* __restrict__ A,
                                                    const ushort_t* __restrict__ W,
                                                    const float* __restrict__ bias1,
                                                    const float* __restrict__ bias2,
                                                    OT* __restrict__ C, int M, int N, int K) {
  int tid = threadIdx.x;
  int l = tid & 63, w = tid >> 6;
  int wm = w >> 1, wn = w & 1;
  int row0 = blockIdx.y * 64 + wm * 32;
  int col0 = blockIdx.x * 64 + wn * 32;
  int lr = l & 15;
  int kb = (l >> 4) << 3;
  int ar0 = row0 + lr, ar1 = row0 + 16 + lr;
  int wr0 = col0 + lr, wr1 = col0 + 16 + lr;
  bool aok0 = ar0 < M, aok1 = ar1 < M;
  bool wok0 = wr0 < N, wok1 = wr1 < N;
  f32x4 acc00 = {0.f, 0.f, 0.f, 0.f}, acc01 = acc00, acc10 = acc00, acc11 = acc00;
#pragma unroll 2
  for (int k0 = 0; k0 < K; k0 += 32) {
    int k = k0 + kb;
    short8 a0 = aok0 ? *reinterpret_cast<const short8*>(A + (size_t)ar0 * K + k) : zero8();
    short8 a1 = aok1 ? *reinterpret_cast<const short8*>(A + (size_t)ar1 * K + k) : zero8();
    short8 b0 = wok0 ? *reinterpret_cast<const short8*>(W + (size_t)wr0 * K + k) : zero8();
    short8 b1 = wok1 ? *reinterpret_cast<const short8*>(W + (size_t)wr1 * K + k) : zero8();
    acc00 = __builtin_amdgcn_mfma_f32_16x16x32_bf16(a0, b0, acc00, 0, 0, 0);
    acc01 = __builtin_amdgcn_mfma_f32_16x16x32_bf16(a0, b1, acc01, 0, 0, 0);
    acc10 = __builtin_amdgcn_mfma_f32_16x16x32_bf16(a1, b0, acc10, 0, 0, 0);
    acc11 = __builtin_amdgcn_mfma_f32_16x16x32_bf16(a1, b1, acc11, 0, 0, 0);
  }
  int rb = (l >> 4) << 2;
#pragma unroll
  for (int i = 0; i < 2; ++i) {
#pragma unroll
    for (int v = 0; v < 4; ++v) {
      int r = row0 + i * 16 + rb + v;
      if (r < M) {
#pragma unroll
        for (int j = 0; j < 2; ++j) {
          int cc = col0 + j * 16 + lr;
          if (cc < N) {
            float av;
            if (i == 0) av = (j == 0) ? acc00[v] : acc01[v];
            else        av = (j == 0) ? acc10[v] : acc11[v];
            if (bias1) av += bias1[cc];
            if (bias2) av += bias2[cc];
            store_c(C, (size_t)r * N + cc, av);
          }
        }
      }
    }
  }
}

// ---------------- Q/K/V fused projection. z=0: Q with inline embedding gather. --------
__global__ __launch_bounds__(256) void gemm_qkv(const int* __restrict__ cap,
                                                const float* __restrict__ emb_table,
                                                const ushort_t* __restrict__ hse1,
                                                const ushort_t* __restrict__ ainw,
                                                const float* __restrict__ ainb,
                                                float* __restrict__ Qf, float* __restrict__ Kf,
                                                float* __restrict__ Vf) {
  int z = blockIdx.z;
  if (z == 0 && blockIdx.y >= 19) return;
  const ushort_t* W = ainw + (size_t)z * H_ * H_;
  const float* bias = ainb + z * H_;
  float* C = (z == 0) ? Qf : ((z == 1) ? Kf : Vf);
  int tid = threadIdx.x;
  int l = tid & 63, w = tid >> 6;
  int wm = w >> 1, wn = w & 1;
  int row0 = blockIdx.y * 64 + wm * 32;
  int col0 = blockIdx.x * 64 + wn * 32;
  int lr = l & 15;
  int kb = (l >> 4) << 3;
  int ar0 = row0 + lr, ar1 = row0 + 16 + lr;
  const ushort_t* b0p = W + (size_t)(col0 + lr) * H_ + kb;
  const ushort_t* b1p = W + (size_t)(col0 + 16 + lr) * H_ + kb;
  f32x4 acc00 = {0.f, 0.f, 0.f, 0.f}, acc01 = acc00, acc10 = acc00, acc11 = acc00;
  if (z == 0) {
    int b0 = ar0 / TD_, t0 = ar0 - b0 * TD_;
    int b1 = ar1 / TD_, t1 = ar1 - b1 * TD_;
    const float* a0base = emb_table + (size_t)cap[b0 * 20 + t0] * H_ + kb;
    const float* a1base = emb_table + (size_t)cap[b1 * 20 + t1] * H_ + kb;
#pragma unroll 2
    for (int k0 = 0; k0 < H_; k0 += 32) {
      short8 a0 = cvt_frag(a0base + k0);
      short8 a1 = cvt_frag(a1base + k0);
      short8 bb0 = *reinterpret_cast<const short8*>(b0p + k0);
      short8 bb1 = *reinterpret_cast<const short8*>(b1p + k0);
      acc00 = __builtin_amdgcn_mfma_f32_16x16x32_bf16(a0, bb0, acc00, 0, 0, 0);
      acc01 = __builtin_amdgcn_mfma_f32_16x16x32_bf16(a0, bb1, acc01, 0, 0, 0);
      acc10 = __builtin_amdgcn_mfma_f32_16x16x32_bf16(a1, bb0, acc10, 0, 0, 0);
      acc11 = __builtin_amdgcn_mfma_f32_16x16x32_bf16(a1, bb1, acc11, 0, 0, 0);
    }
  } else {
    const ushort_t* a0p = hse1 + (size_t)ar0 * H_ + kb;
    const ushort_t* a1p = hse1 + (size_t)ar1 * H_ + kb;
#pragma unroll 2
    for (int k0 = 0; k0 < H_; k0 += 32) {
      short8 a0 = *reinterpret_cast<const short8*>(a0p + k0);
      short8 a1 = *reinterpret_cast<const short8*>(a1p + k0);
      short8 bb0 = *reinterpret_cast<const short8*>(b0p + k0);
      short8 bb1 = *reinterpret_cast<const short8*>(b1p + k0);
      acc00 = __builtin_amdgcn_mfma_f32_16x16x32_bf16(a0, bb0, acc00, 0, 0, 0);
      acc01 = __builtin_amdgcn_mfma_f32_16x16x32_bf16(a0, bb1, acc01, 0, 0, 0);
      acc10 = __builtin_amdgcn_mfma_f32_16x16x32_bf16(a1, bb0, acc10, 0, 0, 0);
      acc11 = __builtin_amdgcn_mfma_f32_16x16x32_bf16(a1, bb1, acc11, 0, 0, 0);
    }
  }
  int rb = (l >> 4) << 2;
#pragma unroll
  for (int i = 0; i < 2; ++i)
#pragma unroll
    for (int v = 0; v < 4; ++v) {
      int r = row0 + i * 16 + rb + v;
#pragma unroll
      for (int j = 0; j < 2; ++j) {
        int cc = col0 + j * 16 + lr;
        float av;
        if (i == 0) av = (j == 0) ? acc00[v] : acc01[v];
        else        av = (j == 0) ? acc10[v] : acc11[v];
        C[(size_t)r * H_ + cc] = av + bias[cc];
      }
    }
}

// ---------------- big-tile GEMM (64 rows x 256 cols / block) ----------------
template <typename OT>
__global__ __launch_bounds__(256) void gemm_nt_big(const ushort_t* __restrict__ A,
                                                   const ushort_t* __restrict__ W,
                                                   const float* __restrict__ bias1,
                                                   const float* __restrict__ bias2,
                                                   OT* __restrict__ C, int M, int N, int K) {
  int tid = threadIdx.x;
  int l = tid & 63, w = tid >> 6;
  int row0 = blockIdx.y * 64;
  int col0 = blockIdx.x * 256 + w * 64;
  int lr = l & 15, kb = (l >> 4) << 3;
  f32x4 acc[4][4];
#pragma unroll
  for (int i = 0; i < 4; ++i)
#pragma unroll
    for (int j = 0; j < 4; ++j) acc[i][j] = (f32x4){0.f, 0.f, 0.f, 0.f};
  const ushort_t* aps[4];
  const ushort_t* wps[4];
  bool wok[4];
#pragma unroll
  for (int fi = 0; fi < 4; ++fi) aps[fi] = A + (size_t)(row0 + fi * 16 + lr) * K + kb;
#pragma unroll
  for (int fj = 0; fj < 4; ++fj) {
    int wr = col0 + fj * 16 + lr;
    wok[fj] = wr < N;
    wps[fj] = W + (size_t)(wok[fj] ? wr : 0) * K + kb;
  }
#pragma unroll 2
  for (int k0 = 0; k0 < K; k0 += 32) {
    short8 af[4], bf[4];
#pragma unroll
    for (int fi = 0; fi < 4; ++fi) af[fi] = *reinterpret_cast<const short8*>(aps[fi] + k0);
#pragma unroll
    for (int fj = 0; fj < 4; ++fj)
      bf[fj] = wok[fj] ? *reinterpret_cast<const short8*>(wps[fj] + k0) : zero8();
#pragma unroll
    for (int fi = 0; fi < 4; ++fi)
#pragma unroll
      for (int fj = 0; fj < 4; ++fj)
        acc[fi][fj] = __builtin_amdgcn_mfma_f32_16x16x32_bf16(af[fi], bf[fj], acc[fi][fj], 0, 0, 0);
  }
  int rb = (l >> 4) << 2;
#pragma unroll
  for (int fi = 0; fi < 4; ++fi) {
#pragma unroll
    for (int v = 0; v < 4; ++v) {
      int r = row0 + fi * 16 + rb + v;
#pragma unroll
      for (int fj = 0; fj < 4; ++fj) {
        int cc = col0 + fj * 16 + lr;
        if (cc < N) {
          float av = acc[fi][fj][v];
          if (bias1) av += bias1[cc];
          if (bias2) av += bias2[cc];
          store_c(C, (size_t)r * N + cc, av);
        }
      }
    }
  }
}

// ---------------- split-K big GEMM with fp32 atomic accumulation ----------------
__global__ __launch_bounds__(256) void gemm_nt_big_split(const ushort_t* __restrict__ A,
                                                         const ushort_t* __restrict__ W,
                                                         float* __restrict__ C, int M, int N,
                                                         int K, int kc) {
  int tid = threadIdx.x;
  int l = tid & 63, w = tid >> 6;
  int row0 = blockIdx.y * 64;
  int col0 = blockIdx.x * 256 + w * 64;
  int lr = l & 15, kb = (l >> 4) << 3;
  int kbeg = blockIdx.z * kc;
  f32x4 acc[4][4];
#pragma unroll
  for (int i = 0; i < 4; ++i)
#pragma unroll
    for (int j = 0; j < 4; ++j) acc[i][j] = (f32x4){0.f, 0.f, 0.f, 0.f};
  const ushort_t* aps[4];
  const ushort_t* wps[4];
#pragma unroll
  for (int fi = 0; fi < 4; ++fi)
    aps[fi] = A + (size_t)(row0 + fi * 16 + lr) * K + kbeg + kb;
#pragma unroll
  for (int fj = 0; fj < 4; ++fj)
    wps[fj] = W + (size_t)(col0 + fj * 16 + lr) * K + kbeg + kb;
#pragma unroll 2
  for (int k0 = 0; k0 < kc; k0 += 32) {
    short8 af[4], bf[4];
#pragma unroll
    for (int fi = 0; fi < 4; ++fi) af[fi] = *reinterpret_cast<const short8*>(aps[fi] + k0);
#pragma unroll
    for (int fj = 0; fj < 4; ++fj) bf[fj] = *reinterpret_cast<const short8*>(wps[fj] + k0);
#pragma unroll
    for (int fi = 0; fi < 4; ++fi)
#pragma unroll
      for (int fj = 0; fj < 4; ++fj)
        acc[fi][fj] = __builtin_amdgcn_mfma_f32_16x16x32_bf16(af[fi], bf[fj], acc[fi][fj], 0, 0, 0);
  }
  int rb = (l >> 4) << 2;
#pragma unroll
  for (int fi = 0; fi < 4; ++fi)
#pragma unroll
    for (int v = 0; v < 4; ++v) {
      int r = row0 + fi * 16 + rb + v;
#pragma unroll
      for (int fj = 0; fj < 4; ++fj) {
        int cc = col0 + fj * 16 + lr;
        atomicAdd(&C[(size_t)r * N + cc], acc[fi][fj][v]);
      }
    }
}

// add column-bias + cvt to bf16 (vproj epilogue)
__global__ __launch_bounds__(256) void bias_cvt_bf16(const float* __restrict__ in,
                                                     const float* __restrict__ bias,
                                                     ushort_t* __restrict__ outp, int ncols,
                                                     int n4) {
  int i = blockIdx.x * 256 + threadIdx.x;
  if (i < n4) {
    float4 v = reinterpret_cast<const float4*>(in)[i];
    int col = (i * 4) & (ncols - 1);
    float4 bv = *reinterpret_cast<const float4*>(bias + col);
    ushort4 r;
    r.x = f2bf(v.x + bv.x); r.y = f2bf(v.y + bv.y);
    r.z = f2bf(v.z + bv.z); r.w = f2bf(v.w + bv.w);
    reinterpret_cast<ushort4*>(outp)[i] = r;
  }
}

// ---------------- epoch-flag wait: wave 0 polls 128 spread flags (PROVEN R11) ----------
__device__ __forceinline__ void wait_flags2(const int* __restrict__ fA, int tA,
                                            const int* __restrict__ fB, int tB, int tid) {
  if (tid < 64) {
    for (;;) {
      int a0 = __hip_atomic_load(fA + tid * 16, __ATOMIC_RELAXED, __HIP_MEMORY_SCOPE_AGENT);
      int a1 = __hip_atomic_load(fA + (tid + 64) * 16, __ATOMIC_RELAXED, __HIP_MEMORY_SCOPE_AGENT);
      bool ok = (a0 >= tA) && (a1 >= tA);
      if (fB) {
        int b0 = __hip_atomic_load(fB + tid * 16, __ATOMIC_RELAXED, __HIP_MEMORY_SCOPE_AGENT);
        int b1 = __hip_atomic_load(fB + (tid + 64) * 16, __ATOMIC_RELAXED, __HIP_MEMORY_SCOPE_AGENT);
        ok = ok && (b0 >= tB) && (b1 >= tB);
      }
      if (__all(ok)) break;
      __builtin_amdgcn_s_sleep(2);
    }
  }
  __syncthreads();
}

// ---------------- persistent diagonal LSTM pair (R13 core + hi-only x-ring) ------------
// As R13 except B's x-term reads the 2B/elem hi-only ringX (written by role A via the
// R7-proven shfl_down pair-pack) instead of the 4B/elem packed ringA slot: per-XCD
// per-step MALL fill drops 384->320KB and B no longer contends on ringA's next slot.
__global__ __launch_bounds__(512, 2) void lstm_ring(
    const float* __restrict__ xg, const ushort_t* __restrict__ whhA_hi,
    const ushort_t* __restrict__ whhA_lo, const ushort_t* __restrict__ whhB_hi,
    const ushort_t* __restrict__ whhB_lo, const ushort_t* __restrict__ wihB,
    const float* __restrict__ bcB, unsigned int* __restrict__ ringA,
    unsigned int* __restrict__ ringB, unsigned int* __restrict__ ringX,
    ushort_t* __restrict__ hsB, int T, int* __restrict__ flagA, int* __restrict__ flagB) {
  __shared__ float gbuf[2][64][17];
  const int role = (int)(blockIdx.x >> 7);  // 0 = layer A, 1 = layer B
  const int tile = (int)(blockIdx.x & 127);
  const int tid = (int)threadIdx.x;
  const int g2 = tid >> 8;                 // K-half
  const int u = tid & 255;
  const int l = u & 63, w = u >> 6;
  const int lr = l & 15, kq = l >> 4;
  const int kb = g2 * 256 + (kq << 3);     // K element offset
  const int arow = (w << 4) + lr;
  const int prow = tile * 16 + lr;
  const int row = tid >> 2, s = tid & 3;   // gate phase (tid<256)
  const int col = (tile << 2) + s;
  unsigned int* ring_own = role ? ringB : ringA;
  int* flag_own = (role ? flagB : flagA) + tile * 16;

  short8 wb[8], wbl[8];
  {
    const ushort_t* bp = (role ? whhB_hi : whhA_hi) + (size_t)prow * H_ + kb;
    const ushort_t* blp = (role ? whhB_lo : whhA_lo) + (size_t)prow * H_ + kb;
#pragma unroll
    for (int i = 0; i < 8; ++i) {
      wb[i] = *reinterpret_cast<const short8*>(bp + i * 32);
      wbl[i] = *reinterpret_cast<const short8*>(blp + i * 32);
    }
  }
  const ushort_t* wpp = wihB + (size_t)prow * H_ + kb;
  float bci = 0.f, bcf = 0.f, bcg = 0.f, bco = 0.f;
  if (role && tid < 256) {
    bci = bcB[tile * 16 + 0 + s];
    bcf = bcB[tile * 16 + 4 + s];
    bcg = bcB[tile * 16 + 8 + s];
    bco = bcB[tile * 16 + 12 + s];
  }
  float creg = 0.f;
  for (int t = 0; t < T; ++t) {
    float xgi = 0.f, xgf = 0.f, xgg = 0.f, xgo = 0.f;
    if (!role && tid < 256) {
      size_t xb = ((size_t)row * T + t) * (size_t)G4_ + col;
      xgi = xg[xb]; xgf = xg[xb + 512]; xgg = xg[xb + 1024]; xgo = xg[xb + 1536];
    }
    if (role == 0) {
      if (t > 0) wait_flags2(flagA, t, nullptr, 0, tid);
      else __syncthreads();
    } else {
      wait_flags2(flagA, t + 1, (t > 0) ? flagB : nullptr, t, tid);
    }
    const unsigned int* rh = ring_own + (size_t)t * HN_ + (size_t)arow * H_ + kb;
    f32x4 a0 = {0.f, 0.f, 0.f, 0.f}, a1 = a0, a2 = a0, a3 = a0;
    if (role == 0) {
      uint4 q[16];
#pragma unroll
      for (int i = 0; i < 8; ++i) {
        q[2 * i] = *reinterpret_cast<const uint4*>(rh + i * 32);
        q[2 * i + 1] = *reinterpret_cast<const uint4*>(rh + i * 32 + 4);
      }
#pragma unroll
      for (int i = 0; i < 8; ++i) {
        short8 a = unpack_hi(q[2 * i], q[2 * i + 1]);
        short8 al = unpack_lo(q[2 * i], q[2 * i + 1]);
        a0 = __builtin_amdgcn_mfma_f32_16x16x32_bf16(a, wb[i], a0, 0, 0, 0);
        a1 = __builtin_amdgcn_mfma_f32_16x16x32_bf16(al, wb[i], a1, 0, 0, 0);
        a2 = __builtin_amdgcn_mfma_f32_16x16x32_bf16(a, wbl[i], a2, 0, 0, 0);
      }
    } else {
      const unsigned int* rxp =
          ringX + (size_t)(t + 1) * XN_ + (size_t)arow * 256 + (kb >> 1);
      uint4 q[16], x[8];
#pragma unroll
      for (int i = 0; i < 8; ++i) {
        q[2 * i] = *reinterpret_cast<const uint4*>(rh + i * 32);
        q[2 * i + 1] = *reinterpret_cast<const uint4*>(rh + i * 32 + 4);
      }
#pragma unroll
      for (int i = 0; i < 8; ++i) x[i] = *reinterpret_cast<const uint4*>(rxp + i * 16);
#pragma unroll
      for (int i = 0; i < 8; ++i) {
        short8 a = unpack_hi(q[2 * i], q[2 * i + 1]);
        short8 al = unpack_lo(q[2 * i], q[2 * i + 1]);
        union { uint4 u; short8 s8; } xv;
        xv.u = x[i];
        short8 wx = *reinterpret_cast<const short8*>(wpp + i * 32);
        a0 = __builtin_amdgcn_mfma_f32_16x16x32_bf16(a, wb[i], a0, 0, 0, 0);
        a1 = __builtin_amdgcn_mfma_f32_16x16x32_bf16(al, wb[i], a1, 0, 0, 0);
        a2 = __builtin_amdgcn_mfma_f32_16x16x32_bf16(a, wbl[i], a2, 0, 0, 0);
        a3 = __builtin_amdgcn_mfma_f32_16x16x32_bf16(xv.s8, wx, a3, 0, 0, 0);
      }
    }
    f32x4 acc = (a0 + a1) + (a2 + a3);
    const int rb = (w << 4) + (kq << 2);
#pragma unroll
    for (int v = 0; v < 4; ++v) gbuf[g2][rb + v][lr] = acc[v];
    __syncthreads();
    if (tid < 256) {
      float gi = gbuf[0][row][0 + s] + gbuf[1][row][0 + s];
      float gf = gbuf[0][row][4 + s] + gbuf[1][row][4 + s];
      float gg = gbuf[0][row][8 + s] + gbuf[1][row][8 + s];
      float go = gbuf[0][row][12 + s] + gbuf[1][row][12 + s];
      if (role) {
        gi += bci; gf += bcf; gg += bcg; go += bco;
      } else {
        gi += xgi; gf += xgf; gg += xgg; go += xgo;
      }
      float cv = sigmoidf_(gf) * creg + sigmoidf_(gi) * tanhf(gg);
      float hv = sigmoidf_(go) * tanhf(cv);
      creg = cv;
      ushort_t hh = f2bf(hv);
      ushort_t hl = f2bf(hv - bf2f(hh));
      unsigned int pk = (unsigned int)hh | ((unsigned int)hl << 16);
      __hip_atomic_store(ring_own + (size_t)(t + 1) * HN_ + (size_t)row * H_ + col, pk,
                         __ATOMIC_RELAXED, __HIP_MEMORY_SCOPE_AGENT);
      if (role == 0) {
        unsigned int hu = (unsigned int)hh;
        unsigned int hpair = hu | (((unsigned int)__shfl_down(hu, 1)) << 16);
        if ((s & 1) == 0)
          __hip_atomic_store(ringX + (size_t)(t + 1) * XN_ + (size_t)row * 256 + (col >> 1),
                             hpair, __ATOMIC_RELAXED, __HIP_MEMORY_SCOPE_AGENT);
      } else {
        hsB[((size_t)row * T + t) * H_ + col] = hh;
      }
    }
    __syncthreads();  // vmcnt(0) drain of all waves' write-through stores, then barrier
    if (tid == 0)
      __hip_atomic_store(flag_own, t + 1, __ATOMIC_RELAXED, __HIP_MEMORY_SCOPE_AGENT);
  }
}

// ---------------- MHA (fp32) ----------------
__global__ __launch_bounds__(256) void mha_kernel(const float* __restrict__ Qf,
                                                  const float* __restrict__ Kf,
                                                  const float* __restrict__ Vf,
                                                  ushort_t* __restrict__ attnout) {
  __shared__ float Qs[19][132];
  __shared__ float Ks[80][132];
  __shared__ float Ss[19][80];
  int h = blockIdx.x, b = blockIdx.y;
  int tid = threadIdx.x;
  for (int idx = tid; idx < 19 * 128; idx += 256) {
    int q = idx >> 7, d = idx & 127;
    Qs[q][d] = Qf[((size_t)(b * TD_ + q)) * H_ + h * 128 + d];
  }
  for (int idx = tid; idx < 80 * 128; idx += 256) {
    int k = idx >> 7, d = idx & 127;
    Ks[k][d] = Kf[((size_t)(b * TV_ + k)) * H_ + h * 128 + d];
  }
  __syncthreads();
  for (int u = tid; u < 240; u += 256) {
    int k = u / 3, qo = u % 3;
    int q0 = qo * 8;
    int nq = (qo == 2) ? 3 : 8;
    float s[8] = {0.f, 0.f, 0.f, 0.f, 0.f, 0.f, 0.f, 0.f};
    for (int d = 0; d < 128; d += 4) {
      float4 kv = *reinterpret_cast<const float4*>(&Ks[k][d]);
#pragma unroll
      for (int qi = 0; qi < 8; ++qi) {
        if (qi < nq) {
          float4 qv = *reinterpret_cast<const float4*>(&Qs[q0 + qi][d]);
          s[qi] += qv.x * kv.x + qv.y * kv.y + qv.z * kv.z + qv.w * kv.w;
        }
      }
    }
    for (int qi = 0; qi < nq; ++qi) Ss[q0 + qi][k] = s[qi] * 0.08838834764831845f;
  }
  __syncthreads();
  if (tid < 19) {
    float m = -1e30f;
    for (int k = 0; k < 80; ++k) m = fmaxf(m, Ss[tid][k]);
    float sum = 0.f;
    for (int k = 0; k < 80; ++k) {
      float e = expf(Ss[tid][k] - m);
      Ss[tid][k] = e;
      sum += e;
    }
    float inv = 1.0f / sum;
    for (int k = 0; k < 80; ++k) Ss[tid][k] *= inv;
  }
  __syncthreads();
  for (int u = tid; u < 160; u += 256) {
    int qp = u / 16, d0 = (u % 16) * 8;
    int q0 = qp * 2;
    int nq = (q0 + 1 < 19) ? 2 : 1;
    float o0[8] = {0.f, 0.f, 0.f, 0.f, 0.f, 0.f, 0.f, 0.f};
    float o1[8] = {0.f, 0.f, 0.f, 0.f, 0.f, 0.f, 0.f, 0.f};
#pragma unroll 4
    for (int k = 0; k < 80; ++k) {
      const float* vp = Vf + ((size_t)(b * TV_ + k)) * H_ + h * 128 + d0;
      float4 v0 = *reinterpret_cast<const float4*>(vp);
      float4 v1 = *reinterpret_cast<const float4*>(vp + 4);
      float p0 = Ss[q0][k];
      o0[0] += p0 * v0.x; o0[1] += p0 * v0.y; o0[2] += p0 * v0.z; o0[3] += p0 * v0.w;
      o0[4] += p0 * v1.x; o0[5] += p0 * v1.y; o0[6] += p0 * v1.z; o0[7] += p0 * v1.w;
      if (nq == 2) {
        float p1 = Ss[q0 + 1][k];
        o1[0] += p1 * v0.x; o1[1] += p1 * v0.y; o1[2] += p1 * v0.z; o1[3] += p1 * v0.w;
        o1[4] += p1 * v1.x; o1[5] += p1 * v1.y; o1[6] += p1 * v1.z; o1[7] += p1 * v1.w;
      }
    }
    for (int j = 0; j < 8; ++j)
      attnout[((size_t)(b * TD_ + q0)) * H_ + h * 128 + d0 + j] = f2bf(o0[j]);
    if (nq == 2)
      for (int j = 0; j < 8; ++j)
        attnout[((size_t)(b * TD_ + q0 + 1)) * H_ + h * 128 + d0 + j] = f2bf(o1[j]);
  }
}

// ---------------- host ----------------
extern "C" void kernel_launch(void* const* d_in, const int* in_sizes, int n_in, void* d_out,
                              int out_size, void* d_ws, size_t ws_size, hipStream_t stream) {
  const float* video = (const float*)d_in[0];
  const int* captions = (const int*)d_in[1];
  const float* vpw = (const float*)d_in[2];
  const float* vpb = (const float*)d_in[3];
  const float* emb_table = (const float*)d_in[4];
  const float* wih[4] = {(const float*)d_in[5], (const float*)d_in[9], (const float*)d_in[13],
                         (const float*)d_in[17]};
  const float* whh[4] = {(const float*)d_in[6], (const float*)d_in[10], (const float*)d_in[14],
                         (const float*)d_in[18]};
  const float* bih[4] = {(const float*)d_in[7], (const float*)d_in[11], (const float*)d_in[15],
                         (const float*)d_in[19]};
  const float* bhh[4] = {(const float*)d_in[8], (const float*)d_in[12], (const float*)d_in[16],
                         (const float*)d_in[20]};
  const float* a_inw = (const float*)d_in[21];
  const float* a_inb = (const float*)d_in[22];
  const float* a_outw = (const float*)d_in[23];
  const float* a_outb = (const float*)d_in[24];
  const float* ow = (const float*)d_in[25];
  const float* ob = (const float*)d_in[26];
  float* out = (float*)d_out;

  char* ws = (char*)d_ws;
  size_t o = 0;
  auto take = [&](size_t bytes) {
    size_t cur = o;
    o += (bytes + 255) & ~(size_t)255;
    return cur;
  };
  const size_t o_vpw = take((size_t)H_ * VD_ * 2);
  size_t o_wih_std[4], o_whhp_hi[4], o_whhp_lo[4], o_wihp[4], o_bc[4];
  for (int i = 0; i < 4; ++i) {
    o_wih_std[i] = (i == 0 || i == 2) ? take((size_t)G4_ * H_ * 2) : 0;
    o_whhp_hi[i] = take((size_t)G4_ * H_ * 2);
    o_whhp_lo[i] = take((size_t)G4_ * H_ * 2);
    o_wihp[i] = (i == 1 || i == 3) ? take((size_t)G4_ * H_ * 2) : 0;
    o_bc[i] = (i == 1 || i == 3) ? take((size_t)G4_ * 4) : 0;
  }
  const size_t o_ainw = take((size_t)3 * H_ * H_ * 2);
  const size_t o_aoutw = take((size_t)H_ * H_ * 2);
  const size_t o_ow = take((size_t)NV_ * H_ * 2);
  const size_t o_vproj = take((size_t)B_ * TV_ * H_ * 2);
  const size_t o_xg = take((size_t)B_ * TV_ * G4_ * 4);  // video_bf overlay, then xg, then Q/K/V
  const size_t o_hse1 = take((size_t)B_ * TV_ * H_ * 2);
  const size_t o_attn = take((size_t)B_ * TD_ * H_ * 2);
  const size_t o_attd = take((size_t)B_ * TD_ * H_ * 2);
  const size_t o_hsd1 = take((size_t)B_ * TD_ * H_ * 2);
  const size_t o_flags = take(4 * 128 * 64);  // 4 epoch-flag arrays, 64B stride (32KB)
  const size_t o_vpf = take((size_t)B_ * TV_ * H_ * 4);  // vproj fp32 accum
  const size_t o_ringA = take((size_t)(TV_ + 1) * HN_ * 4);
  const size_t o_ringB = take((size_t)(TV_ + 1) * HN_ * 4);
  const size_t o_ringX = take((size_t)(TV_ + 1) * XN_ * 4);  // hi-only x-ring

  ushort_t* vpw_bf = (ushort_t*)(ws + o_vpw);
  ushort_t* ainw_bf = (ushort_t*)(ws + o_ainw);
  ushort_t* aoutw_bf = (ushort_t*)(ws + o_aoutw);
  ushort_t* ow_bf = (ushort_t*)(ws + o_ow);
  ushort_t* vproj_bf = (ushort_t*)(ws + o_vproj);
  float* xg = (float*)(ws + o_xg);
  ushort_t* video_bf = (ushort_t*)(ws + o_xg);  // overlay
  ushort_t* hse1 = (ushort_t*)(ws + o_hse1);
  ushort_t* attn_bf = (ushort_t*)(ws + o_attn);
  ushort_t* attd_bf = (ushort_t*)(ws + o_attd);
  ushort_t* hsd1 = (ushort_t*)(ws + o_hsd1);
  float* Qf = (float*)(ws + o_xg);
  float* Kf = (float*)(ws + o_xg + 2490368);
  float* Vf = (float*)(ws + o_xg + 2490368 + 10485760);
  int* flagA0 = (int*)(ws + o_flags);
  int* flagB0 = flagA0 + 2048;
  int* flagA1 = flagA0 + 4096;
  int* flagB1 = flagA0 + 6144;
  float* vpf = (float*)(ws + o_vpf);
  unsigned int* ringA = (unsigned int*)(ws + o_ringA);
  unsigned int* ringB = (unsigned int*)(ws + o_ringB);
  unsigned int* ringX = (unsigned int*)(ws + o_ringX);

  // 1. video cvt
  cvt_f32_bf16<<<dim3(20480), dim3(256), 0, stream>>>(video, video_bf,
                                                      (int)((size_t)B_ * TV_ * VD_ / 4));
  // 2. fused small cvts + zero-fills (+ ringX slot0)
  prep_small<<<dim3(12768), dim3(256), 0, stream>>>(
      vpw, vpw_bf, wih[0], (ushort_t*)(ws + o_wih_std[0]), wih[2],
      (ushort_t*)(ws + o_wih_std[2]), a_inw, ainw_bf, a_outw, aoutw_bf, ow, ow_bf, vpf,
      (float*)(ws + o_flags), (float*)ringA, (float*)ringB, (float*)ringX);
  // 3. fused weight permutes (whh x4 | wih x2 | bias x2)
  prep_weights<<<dim3(G4_, 7), dim3(64), 0, stream>>>(
      whh[0], (ushort_t*)(ws + o_whhp_hi[0]), (ushort_t*)(ws + o_whhp_lo[0]), whh[1],
      (ushort_t*)(ws + o_whhp_hi[1]), (ushort_t*)(ws + o_whhp_lo[1]), whh[2],
      (ushort_t*)(ws + o_whhp_hi[2]), (ushort_t*)(ws + o_whhp_lo[2]), whh[3],
      (ushort_t*)(ws + o_whhp_hi[3]), (ushort_t*)(ws + o_whhp_lo[3]), wih[1],
      (ushort_t*)(ws + o_wihp[1]), wih[3], (ushort_t*)(ws + o_wihp[3]), bih[1], bhh[1],
      (float*)(ws + o_bc[1]), bih[3], bhh[3], (float*)(ws + o_bc[3]));

  // 4-5. vproj: split-K x4 atomic fp32, then +vpb and cvt -> bf16
  gemm_nt_big_split<<<dim3(2, 80, 4), dim3(256), 0, stream>>>(video_bf, vpw_bf, vpf, B_ * TV_,
                                                              H_, VD_, VD_ / 4);
  bias_cvt_bf16<<<dim3((B_ * TV_ * H_ / 4 + 255) / 256), dim3(256), 0, stream>>>(
      vpf, vpb, vproj_bf, H_, B_ * TV_ * H_ / 4);

  // 6. xg0 = vproj @ wih0^T + biases
  gemm_nt_big<float><<<dim3(8, 80), dim3(256), 0, stream>>>(
      vproj_bf, (const ushort_t*)(ws + o_wih_std[0]), bih[0], bhh[0], xg, B_ * TV_, G4_, H_);

  // 7. encoder LSTM pair
  lstm_ring<<<dim3(256), dim3(512), 0, stream>>>(
      xg, (const ushort_t*)(ws + o_whhp_hi[0]), (const ushort_t*)(ws + o_whhp_lo[0]),
      (const ushort_t*)(ws + o_whhp_hi[1]), (const ushort_t*)(ws + o_whhp_lo[1]),
      (const ushort_t*)(ws + o_wihp[1]), (const float*)(ws + o_bc[1]), ringA, ringB, ringX,
      hse1, TV_, flagA0, flagB0);

  // 8. Q (inline embedding gather) + K + V in one dispatch
  gemm_qkv<<<dim3(8, 80, 3), dim3(256), 0, stream>>>(captions, emb_table, hse1, ainw_bf, a_inb,
                                                     Qf, Kf, Vf);

  // 9. MHA
  mha_kernel<<<dim3(4, B_), dim3(256), 0, stream>>>(Qf, Kf, Vf, attn_bf);

  // 10. attention out projection
  gemm_nt_mfma<ushort_t><<<dim3(8, TD_), dim3(256), 0, stream>>>(
      attn_bf, aoutw_bf, a_outb, nullptr, attd_bf, B_ * TD_, H_, H_);
  // 11. xg2 = attd @ wih2^T + biases (clobbers Q/K/V overlay — dead)
  gemm_nt_big<float><<<dim3(8, TD_), dim3(256), 0, stream>>>(
      attd_bf, (const ushort_t*)(ws + o_wih_std[2]), bih[2], bhh[2], xg, B_ * TD_, G4_, H_);

  // 12. decoder LSTM pair
  lstm_ring<<<dim3(256), dim3(512), 0, stream>>>(
      xg, (const ushort_t*)(ws + o_whhp_hi[2]), (const ushort_t*)(ws + o_whhp_lo[2]),
      (const ushort_t*)(ws + o_whhp_hi[3]), (const ushort_t*)(ws + o_whhp_lo[3]),
      (const ushort_t*)(ws + o_wihp[3]), (const float*)(ws + o_bc[3]), ringA, ringB, ringX,
      hsd1, TD_, flagA1, flagB1);

  // 13. logits: (1216,512) x (10000,512)^T + ob
  gemm_nt_big<float><<<dim3((NV_ + 255) / 256, TD_), dim3(256), 0, stream>>>(
      hsd1, ow_bf, ob, nullptr, out, B_ * TD_, NV_, H_);
}

// Round 15
// 1233.611 us; speedup vs baseline: 1.2415x; 1.0654x over previous
//
#include <hip/hip_runtime.h>
#include <hip/hip_bf16.h>
#include <math.h>

typedef unsigned short ushort_t;
typedef __attribute__((ext_vector_type(8))) short short8;
typedef __attribute__((ext_vector_type(4))) float f32x4;

#define B_ 64
#define TV_ 80
#define TD_ 19
#define H_ 512
#define VD_ 4096
#define NV_ 10000
#define G4_ 2048
#define HN_ 32768   // B_*H_ (uints per packed ring slot)
#define XN_ 16384   // B_*H_/2 (uints per hi-only ring slot)

__device__ __forceinline__ float bf2f(ushort_t u) {
  unsigned int x = ((unsigned int)u) << 16;
  float f;
  __builtin_memcpy(&f, &x, 4);
  return f;
}
__device__ __forceinline__ ushort_t f2bf(float f) {
  unsigned int x;
  __builtin_memcpy(&x, &f, 4);
  x = (x + 0x7FFFu + ((x >> 16) & 1u)) >> 16;
  return (ushort_t)x;
}
__device__ __forceinline__ float sigmoidf_(float x) { return 1.0f / (1.0f + expf(-x)); }
__device__ __forceinline__ short8 zero8() {
  short8 z = {0, 0, 0, 0, 0, 0, 0, 0};
  return z;
}
// fp32 pair -> bf16 fragment (for inline gather)
__device__ __forceinline__ short8 cvt_frag(const float* __restrict__ p) {
  float4 v0 = *reinterpret_cast<const float4*>(p);
  float4 v1 = *reinterpret_cast<const float4*>(p + 4);
  short8 r;
  r[0] = (short)f2bf(v0.x); r[1] = (short)f2bf(v0.y);
  r[2] = (short)f2bf(v0.z); r[3] = (short)f2bf(v0.w);
  r[4] = (short)f2bf(v1.x); r[5] = (short)f2bf(v1.y);
  r[6] = (short)f2bf(v1.z); r[7] = (short)f2bf(v1.w);
  return r;
}
// unpack packed (hi | lo<<16) uints into bf16 fragments via v_perm
__device__ __forceinline__ short8 unpack_hi(uint4 q0, uint4 q1) {
  union { unsigned int u[4]; short8 s; } r;
  r.u[0] = __builtin_amdgcn_perm(q0.y, q0.x, 0x05040100u);
  r.u[1] = __builtin_amdgcn_perm(q0.w, q0.z, 0x05040100u);
  r.u[2] = __builtin_amdgcn_perm(q1.y, q1.x, 0x05040100u);
  r.u[3] = __builtin_amdgcn_perm(q1.w, q1.z, 0x05040100u);
  return r.s;
}
__device__ __forceinline__ short8 unpack_lo(uint4 q0, uint4 q1) {
  union { unsigned int u[4]; short8 s; } r;
  r.u[0] = __builtin_amdgcn_perm(q0.y, q0.x, 0x07060302u);
  r.u[1] = __builtin_amdgcn_perm(q0.w, q0.z, 0x07060302u);
  r.u[2] = __builtin_amdgcn_perm(q1.y, q1.x, 0x07060302u);
  r.u[3] = __builtin_amdgcn_perm(q1.w, q1.z, 0x07060302u);
  return r.s;
}

// ---------------- fused prep: video cvt + small cvts + zero-fills (one dispatch) ------
__device__ __forceinline__ void cvt_blk(const float* __restrict__ in,
                                        ushort_t* __restrict__ outp, int local, int tid) {
  int i = local * 256 + tid;
  float4 v = reinterpret_cast<const float4*>(in)[i];
  ushort4 r;
  r.x = f2bf(v.x); r.y = f2bf(v.y); r.z = f2bf(v.z); r.w = f2bf(v.w);
  reinterpret_cast<ushort4*>(outp)[i] = r;
}
// ranges: [0,20480) video | [20480,22528) vpw | [22528,23296) ainw | [23296,23552) aoutw
// [23552,28552) ow | [28552,31112) vpf zero | [31112,31120) flags(32KB)
// [31120,31152) ringA slot0 | [31152,31184) ringB slot0 | [31184,31200) ringX slot0
__global__ __launch_bounds__(256) void prep_small(
    const float* __restrict__ video, ushort_t* __restrict__ video_bf,
    const float* __restrict__ vpw, ushort_t* __restrict__ vpw_bf,
    const float* __restrict__ ainw, ushort_t* __restrict__ ainw_bf,
    const float* __restrict__ aoutw, ushort_t* __restrict__ aoutw_bf,
    const float* __restrict__ ow, ushort_t* __restrict__ ow_bf,
    float* __restrict__ vpf, float* __restrict__ flags, float* __restrict__ ringA0,
    float* __restrict__ ringB0, float* __restrict__ ringX0) {
  int b = (int)blockIdx.x;
  int tid = (int)threadIdx.x;
  if (b < 20480) { cvt_blk(video, video_bf, b, tid); return; }
  if (b < 22528) { cvt_blk(vpw, vpw_bf, b - 20480, tid); return; }
  if (b < 23296) { cvt_blk(ainw, ainw_bf, b - 22528, tid); return; }
  if (b < 23552) { cvt_blk(aoutw, aoutw_bf, b - 23296, tid); return; }
  if (b < 28552) { cvt_blk(ow, ow_bf, b - 23552, tid); return; }
  float4 z = {0.f, 0.f, 0.f, 0.f};
  if (b < 31112) { reinterpret_cast<float4*>(vpf)[(b - 28552) * 256 + tid] = z; return; }
  if (b < 31120) { reinterpret_cast<float4*>(flags)[(b - 31112) * 256 + tid] = z; return; }
  if (b < 31152) { reinterpret_cast<float4*>(ringA0)[(b - 31120) * 256 + tid] = z; return; }
  if (b < 31184) { reinterpret_cast<float4*>(ringB0)[(b - 31152) * 256 + tid] = z; return; }
  reinterpret_cast<float4*>(ringX0)[(b - 31184) * 256 + tid] = z;
}

// ---------------- fused weight prep: whh split x4 | wih permute x4 | bias x4 ----------
// grid (2048, 9), 64 thr. y 0-3: whh layer y; y 4-7: wih layer y-4; y 8: bias (x<128).
__global__ __launch_bounds__(64) void prep_weights(
    const float* __restrict__ s0, ushort_t* __restrict__ h0, ushort_t* __restrict__ l0,
    const float* __restrict__ s1, ushort_t* __restrict__ h1, ushort_t* __restrict__ l1,
    const float* __restrict__ s2, ushort_t* __restrict__ h2, ushort_t* __restrict__ l2,
    const float* __restrict__ s3, ushort_t* __restrict__ h3, ushort_t* __restrict__ l3,
    const float* __restrict__ wi0, ushort_t* __restrict__ wd0, const float* __restrict__ wi1,
    ushort_t* __restrict__ wd1, const float* __restrict__ wi2, ushort_t* __restrict__ wd2,
    const float* __restrict__ wi3, ushort_t* __restrict__ wd3,
    const float* __restrict__ bih0, const float* __restrict__ bhh0, float* __restrict__ bc0,
    const float* __restrict__ bih1, const float* __restrict__ bhh1, float* __restrict__ bc1,
    const float* __restrict__ bih2, const float* __restrict__ bhh2, float* __restrict__ bc2,
    const float* __restrict__ bih3, const float* __restrict__ bhh3, float* __restrict__ bc3) {
  int y = (int)blockIdx.y;
  int p = (int)blockIdx.x;
  int tid = (int)threadIdx.x;
  if (y == 8) {
    if (p >= 128) return;
    int idx = p * 64 + tid;  // 0..8191
    int layer = idx >> 11, q = idx & 2047;
    const float* bih = (layer == 0) ? bih0 : (layer == 1) ? bih1 : (layer == 2) ? bih2 : bih3;
    const float* bhh = (layer == 0) ? bhh0 : (layer == 1) ? bhh1 : (layer == 2) ? bhh2 : bhh3;
    float* bc = (layer == 0) ? bc0 : (layer == 1) ? bc1 : (layer == 2) ? bc2 : bc3;
    int tile = q >> 4, r = q & 15, gate = r >> 2, sc = r & 3;
    int src = gate * H_ + tile * 4 + sc;
    bc[q] = bih[src] + bhh[src];
    return;
  }
  int tile = p >> 4, r = p & 15, gate = r >> 2, sc = r & 3;
  int i = tid * 8;
  if (y >= 4) {
    int ly = y - 4;
    const float* src = (ly == 0) ? wi0 : (ly == 1) ? wi1 : (ly == 2) ? wi2 : wi3;
    ushort_t* hi = (ly == 0) ? wd0 : (ly == 1) ? wd1 : (ly == 2) ? wd2 : wd3;
    const float* s = src + ((size_t)(gate * H_ + tile * 4 + sc)) * H_;
    float4 v0 = *reinterpret_cast<const float4*>(s + i);
    float4 v1 = *reinterpret_cast<const float4*>(s + i + 4);
    ushort_t* hp = hi + (size_t)p * H_ + i;
    ushort4 rh0, rh1;
    rh0.x = f2bf(v0.x); rh0.y = f2bf(v0.y); rh0.z = f2bf(v0.z); rh0.w = f2bf(v0.w);
    rh1.x = f2bf(v1.x); rh1.y = f2bf(v1.y); rh1.z = f2bf(v1.z); rh1.w = f2bf(v1.w);
    reinterpret_cast<ushort4*>(hp)[0] = rh0;
    reinterpret_cast<ushort4*>(hp)[1] = rh1;
    return;
  }
  const float* src = (y == 0) ? s0 : (y == 1) ? s1 : (y == 2) ? s2 : s3;
  ushort_t* hi = (y == 0) ? h0 : (y == 1) ? h1 : (y == 2) ? h2 : h3;
  ushort_t* lo = (y == 0) ? l0 : (y == 1) ? l1 : (y == 2) ? l2 : l3;
  const float* s = src + ((size_t)(gate * H_ + tile * 4 + sc)) * H_;
  float4 v0 = *reinterpret_cast<const float4*>(s + i);
  float4 v1 = *reinterpret_cast<const float4*>(s + i + 4);
  ushort_t* hp = hi + (size_t)p * H_ + i;
  ushort_t* lp = lo + (size_t)p * H_ + i;
  ushort4 rh0, rl0, rh1, rl1;
  rh0.x = f2bf(v0.x); rl0.x = f2bf(v0.x - bf2f(rh0.x));
  rh0.y = f2bf(v0.y); rl0.y = f2bf(v0.y - bf2f(rh0.y));
  rh0.z = f2bf(v0.z); rl0.z = f2bf(v0.z - bf2f(rh0.z));
  rh0.w = f2bf(v0.w); rl0.w = f2bf(v0.w - bf2f(rh0.w));
  rh1.x = f2bf(v1.x); rl1.x = f2bf(v1.x - bf2f(rh1.x));
  rh1.y = f2bf(v1.y); rl1.y = f2bf(v1.y - bf2f(rh1.y));
  rh1.z = f2bf(v1.z); rl1.z = f2bf(v1.z - bf2f(rh1.z));
  rh1.w = f2bf(v1.w); rl1.w = f2bf(v1.w - bf2f(rh1.w));
  reinterpret_cast<ushort4*>(hp)[0] = rh0;
  reinterpret_cast<ushort4*>(hp)[1] = rh1;
  reinterpret_cast<ushort4*>(lp)[0] = rl0;
  reinterpret_cast<ushort4*>(lp)[1] = rl1;
}

// ---------------- small-tile GEMM (64x64/block) ----------------
__device__ __forceinline__ void store_c(float* C, size_t idx, float v) { C[idx] = v; }
__device__ __forceinline__ void store_c(ushort_t* C, size_t idx, float v) { C[idx] = f2bf(v); }

template <typename OT>
__global__ __launch_bounds__(256) void gemm_nt_mfma(const ushort_t* __restrict__ A,
                                                    const ushort_t* __restrict__ W,
                                                    const float* __restrict__ bias1,
                                                    const float* __restrict__ bias2,
                                                    OT* __restrict__ C, int M, int N, int K) {
  int tid = threadIdx.x;
  int l = tid & 63, w = tid >> 6;
  int wm = w >> 1, wn = w & 1;
  int row0 = blockIdx.y * 64 + wm * 32;
  int col0 = blockIdx.x * 64 + wn * 32;
  int lr = l & 15;
  int kb = (l >> 4) << 3;
  int ar0 = row0 + lr, ar1 = row0 + 16 + lr;
  int wr0 = col0 + lr, wr1 = col0 + 16 + lr;
  bool aok0 = ar0 < M, aok1 = ar1 < M;
  bool wok0 = wr0 < N, wok1 = wr1 < N;
  f32x4 acc00 = {0.f, 0.f, 0.f, 0.f}, acc01 = acc00, acc10 = acc00, acc11 = acc00;
#pragma unroll 2
  for (int k0 = 0; k0 < K; k0 += 32) {
    int k = k0 + kb;
    short8 a0 = aok0 ? *reinterpret_cast<const short8*>(A + (size_t)ar0 * K + k) : zero8();
    short8 a1 = aok1 ? *reinterpret_cast<const short8*>(A + (size_t)ar1 * K + k) : zero8();
    short8 b0 = wok0 ? *reinterpret_cast<const short8*>(W + (size_t)wr0 * K + k) : zero8();
    short8 b1 = wok1 ? *reinterpret_cast<const short8*>(W + (size_t)wr1 * K + k) : zero8();
    acc00 = __builtin_amdgcn_mfma_f32_16x16x32_bf16(a0, b0, acc00, 0, 0, 0);
    acc01 = __builtin_amdgcn_mfma_f32_16x16x32_bf16(a0, b1, acc01, 0, 0, 0);
    acc10 = __builtin_amdgcn_mfma_f32_16x16x32_bf16(a1, b0, acc10, 0, 0, 0);
    acc11 = __builtin_amdgcn_mfma_f32_16x16x32_bf16(a1, b1, acc11, 0, 0, 0);
  }
  int rb = (l >> 4) << 2;
#pragma unroll
  for (int i = 0; i < 2; ++i) {
#pragma unroll
    for (int v = 0; v < 4; ++v) {
      int r = row0 + i * 16 + rb + v;
      if (r < M) {
#pragma unroll
        for (int j = 0; j < 2; ++j) {
          int cc = col0 + j * 16 + lr;
          if (cc < N) {
            float av;
            if (i == 0) av = (j == 0) ? acc00[v] : acc01[v];
            else        av = (j == 0) ? acc10[v] : acc11[v];
            if (bias1) av += bias1[cc];
            if (bias2) av += bias2[cc];
            store_c(C, (size_t)r * N + cc, av);
          }
        }
      }
    }
  }
}

// ---------------- Q/K/V fused projection. z=0: Q with inline embedding gather. --------
__global__ __launch_bounds__(256) void gemm_qkv(const int* __restrict__ cap,
                                                const float* __restrict__ emb_table,
                                                const ushort_t* __restrict__ hse1,
                                                const ushort_t* __restrict__ ainw,
                                                const float* __restrict__ ainb,
                                                float* __restrict__ Qf, float* __restrict__ Kf,
                                                float* __restrict__ Vf) {
  int z = blockIdx.z;
  if (z == 0 && blockIdx.y >= 19) return;
  const ushort_t* W = ainw + (size_t)z * H_ * H_;
  const float* bias = ainb + z * H_;
  float* C = (z == 0) ? Qf : ((z == 1) ? Kf : Vf);
  int tid = threadIdx.x;
  int l = tid & 63, w = tid >> 6;
  int wm = w >> 1, wn = w & 1;
  int row0 = blockIdx.y * 64 + wm * 32;
  int col0 = blockIdx.x * 64 + wn * 32;
  int lr = l & 15;
  int kb = (l >> 4) << 3;
  int ar0 = row0 + lr, ar1 = row0 + 16 + lr;
  const ushort_t* b0p = W + (size_t)(col0 + lr) * H_ + kb;
  const ushort_t* b1p = W + (size_t)(col0 + 16 + lr) * H_ + kb;
  f32x4 acc00 = {0.f, 0.f, 0.f, 0.f}, acc01 = acc00, acc10 = acc00, acc11 = acc00;
  if (z == 0) {
    int b0 = ar0 / TD_, t0 = ar0 - b0 * TD_;
    int b1 = ar1 / TD_, t1 = ar1 - b1 * TD_;
    const float* a0base = emb_table + (size_t)cap[b0 * 20 + t0] * H_ + kb;
    const float* a1base = emb_table + (size_t)cap[b1 * 20 + t1] * H_ + kb;
#pragma unroll 2
    for (int k0 = 0; k0 < H_; k0 += 32) {
      short8 a0 = cvt_frag(a0base + k0);
      short8 a1 = cvt_frag(a1base + k0);
      short8 bb0 = *reinterpret_cast<const short8*>(b0p + k0);
      short8 bb1 = *reinterpret_cast<const short8*>(b1p + k0);
      acc00 = __builtin_amdgcn_mfma_f32_16x16x32_bf16(a0, bb0, acc00, 0, 0, 0);
      acc01 = __builtin_amdgcn_mfma_f32_16x16x32_bf16(a0, bb1, acc01, 0, 0, 0);
      acc10 = __builtin_amdgcn_mfma_f32_16x16x32_bf16(a1, bb0, acc10, 0, 0, 0);
      acc11 = __builtin_amdgcn_mfma_f32_16x16x32_bf16(a1, bb1, acc11, 0, 0, 0);
    }
  } else {
    const ushort_t* a0p = hse1 + (size_t)ar0 * H_ + kb;
    const ushort_t* a1p = hse1 + (size_t)ar1 * H_ + kb;
#pragma unroll 2
    for (int k0 = 0; k0 < H_; k0 += 32) {
      short8 a0 = *reinterpret_cast<const short8*>(a0p + k0);
      short8 a1 = *reinterpret_cast<const short8*>(a1p + k0);
      short8 bb0 = *reinterpret_cast<const short8*>(b0p + k0);
      short8 bb1 = *reinterpret_cast<const short8*>(b1p + k0);
      acc00 = __builtin_amdgcn_mfma_f32_16x16x32_bf16(a0, bb0, acc00, 0, 0, 0);
      acc01 = __builtin_amdgcn_mfma_f32_16x16x32_bf16(a0, bb1, acc01, 0, 0, 0);
      acc10 = __builtin_amdgcn_mfma_f32_16x16x32_bf16(a1, bb0, acc10, 0, 0, 0);
      acc11 = __builtin_amdgcn_mfma_f32_16x16x32_bf16(a1, bb1, acc11, 0, 0, 0);
    }
  }
  int rb = (l >> 4) << 2;
#pragma unroll
  for (int i = 0; i < 2; ++i)
#pragma unroll
    for (int v = 0; v < 4; ++v) {
      int r = row0 + i * 16 + rb + v;
#pragma unroll
      for (int j = 0; j < 2; ++j) {
        int cc = col0 + j * 16 + lr;
        float av;
        if (i == 0) av = (j == 0) ? acc00[v] : acc01[v];
        else        av = (j == 0) ? acc10[v] : acc11[v];
        C[(size_t)r * H_ + cc] = av + bias[cc];
      }
    }
}

// ---------------- big-tile GEMM (64 rows x 256 cols / block) ----------------
template <typename OT>
__global__ __launch_bounds__(256) void gemm_nt_big(const ushort_t* __restrict__ A,
                                                   const ushort_t* __restrict__ W,
                                                   const float* __restrict__ bias1,
                                                   const float* __restrict__ bias2,
                                                   OT* __restrict__ C, int M, int N, int K) {
  int tid = threadIdx.x;
  int l = tid & 63, w = tid >> 6;
  int row0 = blockIdx.y * 64;
  int col0 = blockIdx.x * 256 + w * 64;
  int lr = l & 15, kb = (l >> 4) << 3;
  f32x4 acc[4][4];
#pragma unroll
  for (int i = 0; i < 4; ++i)
#pragma unroll
    for (int j = 0; j < 4; ++j) acc[i][j] = (f32x4){0.f, 0.f, 0.f, 0.f};
  const ushort_t* aps[4];
  const ushort_t* wps[4];
  bool wok[4];
#pragma unroll
  for (int fi = 0; fi < 4; ++fi) aps[fi] = A + (size_t)(row0 + fi * 16 + lr) * K + kb;
#pragma unroll
  for (int fj = 0; fj < 4; ++fj) {
    int wr = col0 + fj * 16 + lr;
    wok[fj] = wr < N;
    wps[fj] = W + (size_t)(wok[fj] ? wr : 0) * K + kb;
  }
#pragma unroll 2
  for (int k0 = 0; k0 < K; k0 += 32) {
    short8 af[4], bf[4];
#pragma unroll
    for (int fi = 0; fi < 4; ++fi) af[fi] = *reinterpret_cast<const short8*>(aps[fi] + k0);
#pragma unroll
    for (int fj = 0; fj < 4; ++fj)
      bf[fj] = wok[fj] ? *reinterpret_cast<const short8*>(wps[fj] + k0) : zero8();
#pragma unroll
    for (int fi = 0; fi < 4; ++fi)
#pragma unroll
      for (int fj = 0; fj < 4; ++fj)
        acc[fi][fj] = __builtin_amdgcn_mfma_f32_16x16x32_bf16(af[fi], bf[fj], acc[fi][fj], 0, 0, 0);
  }
  int rb = (l >> 4) << 2;
#pragma unroll
  for (int fi = 0; fi < 4; ++fi) {
#pragma unroll
    for (int v = 0; v < 4; ++v) {
      int r = row0 + fi * 16 + rb + v;
#pragma unroll
      for (int fj = 0; fj < 4; ++fj) {
        int cc = col0 + fj * 16 + lr;
        if (cc < N) {
          float av = acc[fi][fj][v];
          if (bias1) av += bias1[cc];
          if (bias2) av += bias2[cc];
          store_c(C, (size_t)r * N + cc, av);
        }
      }
    }
  }
}

// ---------------- split-K big GEMM with fp32 atomic accumulation ----------------
__global__ __launch_bounds__(256) void gemm_nt_big_split(const ushort_t* __restrict__ A,
                                                         const ushort_t* __restrict__ W,
                                                         float* __restrict__ C, int M, int N,
                                                         int K, int kc) {
  int tid = threadIdx.x;
  int l = tid & 63, w = tid >> 6;
  int row0 = blockIdx.y * 64;
  int col0 = blockIdx.x * 256 + w * 64;
  int lr = l & 15, kb = (l >> 4) << 3;
  int kbeg = blockIdx.z * kc;
  f32x4 acc[4][4];
#pragma unroll
  for (int i = 0; i < 4; ++i)
#pragma unroll
    for (int j = 0; j < 4; ++j) acc[i][j] = (f32x4){0.f, 0.f, 0.f, 0.f};
  const ushort_t* aps[4];
  const ushort_t* wps[4];
#pragma unroll
  for (int fi = 0; fi < 4; ++fi)
    aps[fi] = A + (size_t)(row0 + fi * 16 + lr) * K + kbeg + kb;
#pragma unroll
  for (int fj = 0; fj < 4; ++fj)
    wps[fj] = W + (size_t)(col0 + fj * 16 + lr) * K + kbeg + kb;
#pragma unroll 2
  for (int k0 = 0; k0 < kc; k0 += 32) {
    short8 af[4], bf[4];
#pragma unroll
    for (int fi = 0; fi < 4; ++fi) af[fi] = *reinterpret_cast<const short8*>(aps[fi] + k0);
#pragma unroll
    for (int fj = 0; fj < 4; ++fj) bf[fj] = *reinterpret_cast<const short8*>(wps[fj] + k0);
#pragma unroll
    for (int fi = 0; fi < 4; ++fi)
#pragma unroll
      for (int fj = 0; fj < 4; ++fj)
        acc[fi][fj] = __builtin_amdgcn_mfma_f32_16x16x32_bf16(af[fi], bf[fj], acc[fi][fj], 0, 0, 0);
  }
  int rb = (l >> 4) << 2;
#pragma unroll
  for (int fi = 0; fi < 4; ++fi)
#pragma unroll
    for (int v = 0; v < 4; ++v) {
      int r = row0 + fi * 16 + rb + v;
#pragma unroll
      for (int fj = 0; fj < 4; ++fj) {
        int cc = col0 + fj * 16 + lr;
        atomicAdd(&C[(size_t)r * N + cc], acc[fi][fj][v]);
      }
    }
}

// add column-bias + cvt to bf16 (vproj epilogue)
__global__ __launch_bounds__(256) void bias_cvt_bf16(const float* __restrict__ in,
                                                     const float* __restrict__ bias,
                                                     ushort_t* __restrict__ outp, int ncols,
                                                     int n4) {
  int i = blockIdx.x * 256 + threadIdx.x;
  if (i < n4) {
    float4 v = reinterpret_cast<const float4*>(in)[i];
    int col = (i * 4) & (ncols - 1);
    float4 bv = *reinterpret_cast<const float4*>(bias + col);
    ushort4 r;
    r.x = f2bf(v.x + bv.x); r.y = f2bf(v.y + bv.y);
    r.z = f2bf(v.z + bv.z); r.w = f2bf(v.w + bv.w);
    reinterpret_cast<ushort4*>(outp)[i] = r;
  }
}

// ---------------- epoch-flag wait: wave 0 polls 128 spread flags (PROVEN R11) ----------
__device__ __forceinline__ void wait_flags2(const int* __restrict__ fA, int tA,
                                            const int* __restrict__ fB, int tB, int tid) {
  if (tid < 64) {
    for (;;) {
      int a0 = __hip_atomic_load(fA + tid * 16, __ATOMIC_RELAXED, __HIP_MEMORY_SCOPE_AGENT);
      int a1 = __hip_atomic_load(fA + (tid + 64) * 16, __ATOMIC_RELAXED, __HIP_MEMORY_SCOPE_AGENT);
      bool ok = (a0 >= tA) && (a1 >= tA);
      if (fB) {
        int b0 = __hip_atomic_load(fB + tid * 16, __ATOMIC_RELAXED, __HIP_MEMORY_SCOPE_AGENT);
        int b1 = __hip_atomic_load(fB + (tid + 64) * 16, __ATOMIC_RELAXED, __HIP_MEMORY_SCOPE_AGENT);
        ok = ok && (b0 >= tB) && (b1 >= tB);
      }
      if (__all(ok)) break;
      __builtin_amdgcn_s_sleep(2);
    }
  }
  __syncthreads();
}

// ---------------- persistent diagonal LSTM pair (R14 core + symmetric x-term) ----------
// Both roles compute their x-term inline with a 4th MFMA accumulator:
//   role A: x from xsrcA (static bf16 activations: vproj_bf / attd_bf, row = arow*T + t),
//           weights wihA (permuted), bias bcA. No sync needed (static buffer).
//   role B: x from hi-only ringX slot t+1 (A's h at step t), weights wihB, bias bcB.
// This removes the standalone xg GEMMs; A's extra work hides under B's equal-length path.
__global__ __launch_bounds__(512, 2) void lstm_ring(
    const ushort_t* __restrict__ xsrcA, const ushort_t* __restrict__ wihA,
    const float* __restrict__ bcA, const ushort_t* __restrict__ whhA_hi,
    const ushort_t* __restrict__ whhA_lo, const ushort_t* __restrict__ whhB_hi,
    const ushort_t* __restrict__ whhB_lo, const ushort_t* __restrict__ wihB,
    const float* __restrict__ bcB, unsigned int* __restrict__ ringA,
    unsigned int* __restrict__ ringB, unsigned int* __restrict__ ringX,
    ushort_t* __restrict__ hsB, int T, int* __restrict__ flagA, int* __restrict__ flagB) {
  __shared__ float gbuf[2][64][17];
  const int role = (int)(blockIdx.x >> 7);  // 0 = layer A, 1 = layer B
  const int tile = (int)(blockIdx.x & 127);
  const int tid = (int)threadIdx.x;
  const int g2 = tid >> 8;                 // K-half
  const int u = tid & 255;
  const int l = u & 63, w = u >> 6;
  const int lr = l & 15, kq = l >> 4;
  const int kb = g2 * 256 + (kq << 3);     // K element offset
  const int arow = (w << 4) + lr;
  const int prow = tile * 16 + lr;
  const int row = tid >> 2, s = tid & 3;   // gate phase (tid<256)
  const int col = (tile << 2) + s;
  unsigned int* ring_own = role ? ringB : ringA;
  int* flag_own = (role ? flagB : flagA) + tile * 16;

  short8 wb[8], wbl[8];
  {
    const ushort_t* bp = (role ? whhB_hi : whhA_hi) + (size_t)prow * H_ + kb;
    const ushort_t* blp = (role ? whhB_lo : whhA_lo) + (size_t)prow * H_ + kb;
#pragma unroll
    for (int i = 0; i < 8; ++i) {
      wb[i] = *reinterpret_cast<const short8*>(bp + i * 32);
      wbl[i] = *reinterpret_cast<const short8*>(blp + i * 32);
    }
  }
  const ushort_t* wpp = (role ? wihB : wihA) + (size_t)prow * H_ + kb;
  float bci = 0.f, bcf = 0.f, bcg = 0.f, bco = 0.f;
  if (tid < 256) {
    const float* bc = role ? bcB : bcA;
    bci = bc[tile * 16 + 0 + s];
    bcf = bc[tile * 16 + 4 + s];
    bcg = bc[tile * 16 + 8 + s];
    bco = bc[tile * 16 + 12 + s];
  }
  float creg = 0.f;
  for (int t = 0; t < T; ++t) {
    if (role == 0) {
      if (t > 0) wait_flags2(flagA, t, nullptr, 0, tid);
      else __syncthreads();
    } else {
      wait_flags2(flagA, t + 1, (t > 0) ? flagB : nullptr, t, tid);
    }
    const unsigned int* rh = ring_own + (size_t)t * HN_ + (size_t)arow * H_ + kb;
    f32x4 a0 = {0.f, 0.f, 0.f, 0.f}, a1 = a0, a2 = a0, a3 = a0;
    if (role == 0) {
      const ushort_t* xp = xsrcA + ((size_t)arow * T + t) * H_ + kb;
      uint4 q[16];
#pragma unroll
      for (int i = 0; i < 8; ++i) {
        q[2 * i] = *reinterpret_cast<const uint4*>(rh + i * 32);
        q[2 * i + 1] = *reinterpret_cast<const uint4*>(rh + i * 32 + 4);
      }
#pragma unroll
      for (int i = 0; i < 8; ++i) {
        short8 a = unpack_hi(q[2 * i], q[2 * i + 1]);
        short8 al = unpack_lo(q[2 * i], q[2 * i + 1]);
        short8 xf = *reinterpret_cast<const short8*>(xp + i * 32);
        short8 wx = *reinterpret_cast<const short8*>(wpp + i * 32);
        a0 = __builtin_amdgcn_mfma_f32_16x16x32_bf16(a, wb[i], a0, 0, 0, 0);
        a1 = __builtin_amdgcn_mfma_f32_16x16x32_bf16(al, wb[i], a1, 0, 0, 0);
        a2 = __builtin_amdgcn_mfma_f32_16x16x32_bf16(a, wbl[i], a2, 0, 0, 0);
        a3 = __builtin_amdgcn_mfma_f32_16x16x32_bf16(xf, wx, a3, 0, 0, 0);
      }
    } else {
      const unsigned int* rxp =
          ringX + (size_t)(t + 1) * XN_ + (size_t)arow * 256 + (kb >> 1);
      uint4 q[16], x[8];
#pragma unroll
      for (int i = 0; i < 8; ++i) {
        q[2 * i] = *reinterpret_cast<const uint4*>(rh + i * 32);
        q[2 * i + 1] = *reinterpret_cast<const uint4*>(rh + i * 32 + 4);
      }
#pragma unroll
      for (int i = 0; i < 8; ++i) x[i] = *reinterpret_cast<const uint4*>(rxp + i * 16);
#pragma unroll
      for (int i = 0; i < 8; ++i) {
        short8 a = unpack_hi(q[2 * i], q[2 * i + 1]);
        short8 al = unpack_lo(q[2 * i], q[2 * i + 1]);
        union { uint4 u; short8 s8; } xv;
        xv.u = x[i];
        short8 wx = *reinterpret_cast<const short8*>(wpp + i * 32);
        a0 = __builtin_amdgcn_mfma_f32_16x16x32_bf16(a, wb[i], a0, 0, 0, 0);
        a1 = __builtin_amdgcn_mfma_f32_16x16x32_bf16(al, wb[i], a1, 0, 0, 0);
        a2 = __builtin_amdgcn_mfma_f32_16x16x32_bf16(a, wbl[i], a2, 0, 0, 0);
        a3 = __builtin_amdgcn_mfma_f32_16x16x32_bf16(xv.s8, wx, a3, 0, 0, 0);
      }
    }
    f32x4 acc = (a0 + a1) + (a2 + a3);
    const int rb = (w << 4) + (kq << 2);
#pragma unroll
    for (int v = 0; v < 4; ++v) gbuf[g2][rb + v][lr] = acc[v];
    __syncthreads();
    if (tid < 256) {
      float gi = gbuf[0][row][0 + s] + gbuf[1][row][0 + s] + bci;
      float gf = gbuf[0][row][4 + s] + gbuf[1][row][4 + s] + bcf;
      float gg = gbuf[0][row][8 + s] + gbuf[1][row][8 + s] + bcg;
      float go = gbuf[0][row][12 + s] + gbuf[1][row][12 + s] + bco;
      float cv = sigmoidf_(gf) * creg + sigmoidf_(gi) * tanhf(gg);
      float hv = sigmoidf_(go) * tanhf(cv);
      creg = cv;
      ushort_t hh = f2bf(hv);
      ushort_t hl = f2bf(hv - bf2f(hh));
      unsigned int pk = (unsigned int)hh | ((unsigned int)hl << 16);
      __hip_atomic_store(ring_own + (size_t)(t + 1) * HN_ + (size_t)row * H_ + col, pk,
                         __ATOMIC_RELAXED, __HIP_MEMORY_SCOPE_AGENT);
      if (role == 0) {
        unsigned int hu = (unsigned int)hh;
        unsigned int hpair = hu | (((unsigned int)__shfl_down(hu, 1)) << 16);
        if ((s & 1) == 0)
          __hip_atomic_store(ringX + (size_t)(t + 1) * XN_ + (size_t)row * 256 + (col >> 1),
                             hpair, __ATOMIC_RELAXED, __HIP_MEMORY_SCOPE_AGENT);
      } else {
        hsB[((size_t)row * T + t) * H_ + col] = hh;
      }
    }
    __syncthreads();  // vmcnt(0) drain of all waves' write-through stores, then barrier
    if (tid == 0)
      __hip_atomic_store(flag_own, t + 1, __ATOMIC_RELAXED, __HIP_MEMORY_SCOPE_AGENT);
  }
}

// ---------------- MHA (fp32) ----------------
__global__ __launch_bounds__(256) void mha_kernel(const float* __restrict__ Qf,
                                                  const float* __restrict__ Kf,
                                                  const float* __restrict__ Vf,
                                                  ushort_t* __restrict__ attnout) {
  __shared__ float Qs[19][132];
  __shared__ float Ks[80][132];
  __shared__ float Ss[19][80];
  int h = blockIdx.x, b = blockIdx.y;
  int tid = threadIdx.x;
  for (int idx = tid; idx < 19 * 128; idx += 256) {
    int q = idx >> 7, d = idx & 127;
    Qs[q][d] = Qf[((size_t)(b * TD_ + q)) * H_ + h * 128 + d];
  }
  for (int idx = tid; idx < 80 * 128; idx += 256) {
    int k = idx >> 7, d = idx & 127;
    Ks[k][d] = Kf[((size_t)(b * TV_ + k)) * H_ + h * 128 + d];
  }
  __syncthreads();
  for (int u = tid; u < 240; u += 256) {
    int k = u / 3, qo = u % 3;
    int q0 = qo * 8;
    int nq = (qo == 2) ? 3 : 8;
    float s[8] = {0.f, 0.f, 0.f, 0.f, 0.f, 0.f, 0.f, 0.f};
    for (int d = 0; d < 128; d += 4) {
      float4 kv = *reinterpret_cast<const float4*>(&Ks[k][d]);
#pragma unroll
      for (int qi = 0; qi < 8; ++qi) {
        if (qi < nq) {
          float4 qv = *reinterpret_cast<const float4*>(&Qs[q0 + qi][d]);
          s[qi] += qv.x * kv.x + qv.y * kv.y + qv.z * kv.z + qv.w * kv.w;
        }
      }
    }
    for (int qi = 0; qi < nq; ++qi) Ss[q0 + qi][k] = s[qi] * 0.08838834764831845f;
  }
  __syncthreads();
  if (tid < 19) {
    float m = -1e30f;
    for (int k = 0; k < 80; ++k) m = fmaxf(m, Ss[tid][k]);
    float sum = 0.f;
    for (int k = 0; k < 80; ++k) {
      float e = expf(Ss[tid][k] - m);
      Ss[tid][k] = e;
      sum += e;
    }
    float inv = 1.0f / sum;
    for (int k = 0; k < 80; ++k) Ss[tid][k] *= inv;
  }
  __syncthreads();
  for (int u = tid; u < 160; u += 256) {
    int qp = u / 16, d0 = (u % 16) * 8;
    int q0 = qp * 2;
    int nq = (q0 + 1 < 19) ? 2 : 1;
    float o0[8] = {0.f, 0.f, 0.f, 0.f, 0.f, 0.f, 0.f, 0.f};
    float o1[8] = {0.f, 0.f, 0.f, 0.f, 0.f, 0.f, 0.f, 0.f};
#pragma unroll 4
    for (int k = 0; k < 80; ++k) {
      const float* vp = Vf + ((size_t)(b * TV_ + k)) * H_ + h * 128 + d0;
      float4 v0 = *reinterpret_cast<const float4*>(vp);
      float4 v1 = *reinterpret_cast<const float4*>(vp + 4);
      float p0 = Ss[q0][k];
      o0[0] += p0 * v0.x; o0[1] += p0 * v0.y; o0[2] += p0 * v0.z; o0[3] += p0 * v0.w;
      o0[4] += p0 * v1.x; o0[5] += p0 * v1.y; o0[6] += p0 * v1.z; o0[7] += p0 * v1.w;
      if (nq == 2) {
        float p1 = Ss[q0 + 1][k];
        o1[0] += p1 * v0.x; o1[1] += p1 * v0.y; o1[2] += p1 * v0.z; o1[3] += p1 * v0.w;
        o1[4] += p1 * v1.x; o1[5] += p1 * v1.y; o1[6] += p1 * v1.z; o1[7] += p1 * v1.w;
      }
    }
    for (int j = 0; j < 8; ++j)
      attnout[((size_t)(b * TD_ + q0)) * H_ + h * 128 + d0 + j] = f2bf(o0[j]);
    if (nq == 2)
      for (int j = 0; j < 8; ++j)
        attnout[((size_t)(b * TD_ + q0 + 1)) * H_ + h * 128 + d0 + j] = f2bf(o1[j]);
  }
}

// ---------------- host ----------------
extern "C" void kernel_launch(void* const* d_in, const int* in_sizes, int n_in, void* d_out,
                              int out_size, void* d_ws, size_t ws_size, hipStream_t stream) {
  const float* video = (const float*)d_in[0];
  const int* captions = (const int*)d_in[1];
  const float* vpw = (const float*)d_in[2];
  const float* vpb = (const float*)d_in[3];
  const float* emb_table = (const float*)d_in[4];
  const float* wih[4] = {(const float*)d_in[5], (const float*)d_in[9], (const float*)d_in[13],
                         (const float*)d_in[17]};
  const float* whh[4] = {(const float*)d_in[6], (const float*)d_in[10], (const float*)d_in[14],
                         (const float*)d_in[18]};
  const float* bih[4] = {(const float*)d_in[7], (const float*)d_in[11], (const float*)d_in[15],
                         (const float*)d_in[19]};
  const float* bhh[4] = {(const float*)d_in[8], (const float*)d_in[12], (const float*)d_in[16],
                         (const float*)d_in[20]};
  const float* a_inw = (const float*)d_in[21];
  const float* a_inb = (const float*)d_in[22];
  const float* a_outw = (const float*)d_in[23];
  const float* a_outb = (const float*)d_in[24];
  const float* ow = (const float*)d_in[25];
  const float* ob = (const float*)d_in[26];
  float* out = (float*)d_out;

  char* ws = (char*)d_ws;
  size_t o = 0;
  auto take = [&](size_t bytes) {
    size_t cur = o;
    o += (bytes + 255) & ~(size_t)255;
    return cur;
  };
  const size_t o_vpw = take((size_t)H_ * VD_ * 2);
  size_t o_whhp_hi[4], o_whhp_lo[4], o_wihp[4], o_bc[4];
  for (int i = 0; i < 4; ++i) {
    o_whhp_hi[i] = take((size_t)G4_ * H_ * 2);
    o_whhp_lo[i] = take((size_t)G4_ * H_ * 2);
    o_wihp[i] = take((size_t)G4_ * H_ * 2);
    o_bc[i] = take((size_t)G4_ * 4);
  }
  const size_t o_ainw = take((size_t)3 * H_ * H_ * 2);
  const size_t o_aoutw = take((size_t)H_ * H_ * 2);
  const size_t o_ow = take((size_t)NV_ * H_ * 2);
  const size_t o_vproj = take((size_t)B_ * TV_ * H_ * 2);
  const size_t o_xg = take((size_t)B_ * TV_ * G4_ * 4);  // video_bf overlay, then Q/K/V
  const size_t o_hse1 = take((size_t)B_ * TV_ * H_ * 2);
  const size_t o_attn = take((size_t)B_ * TD_ * H_ * 2);
  const size_t o_attd = take((size_t)B_ * TD_ * H_ * 2);
  const size_t o_hsd1 = take((size_t)B_ * TD_ * H_ * 2);
  const size_t o_flags = take(4 * 128 * 64);  // 4 epoch-flag arrays, 64B stride (32KB)
  const size_t o_vpf = take((size_t)B_ * TV_ * H_ * 4);  // vproj fp32 accum
  const size_t o_ringA = take((size_t)(TV_ + 1) * HN_ * 4);
  const size_t o_ringB = take((size_t)(TV_ + 1) * HN_ * 4);
  const size_t o_ringX = take((size_t)(TV_ + 1) * XN_ * 4);  // hi-only x-ring

  ushort_t* vpw_bf = (ushort_t*)(ws + o_vpw);
  ushort_t* ainw_bf = (ushort_t*)(ws + o_ainw);
  ushort_t* aoutw_bf = (ushort_t*)(ws + o_aoutw);
  ushort_t* ow_bf = (ushort_t*)(ws + o_ow);
  ushort_t* vproj_bf = (ushort_t*)(ws + o_vproj);
  ushort_t* video_bf = (ushort_t*)(ws + o_xg);  // overlay
  ushort_t* hse1 = (ushort_t*)(ws + o_hse1);
  ushort_t* attn_bf = (ushort_t*)(ws + o_attn);
  ushort_t* attd_bf = (ushort_t*)(ws + o_attd);
  ushort_t* hsd1 = (ushort_t*)(ws + o_hsd1);
  float* Qf = (float*)(ws + o_xg);
  float* Kf = (float*)(ws + o_xg + 2490368);
  float* Vf = (float*)(ws + o_xg + 2490368 + 10485760);
  int* flagA0 = (int*)(ws + o_flags);
  int* flagB0 = flagA0 + 2048;
  int* flagA1 = flagA0 + 4096;
  int* flagB1 = flagA0 + 6144;
  float* vpf = (float*)(ws + o_vpf);
  unsigned int* ringA = (unsigned int*)(ws + o_ringA);
  unsigned int* ringB = (unsigned int*)(ws + o_ringB);
  unsigned int* ringX = (unsigned int*)(ws + o_ringX);

  // 1. fused prep: video cvt + small cvts + zero-fills
  prep_small<<<dim3(31200), dim3(256), 0, stream>>>(
      video, video_bf, vpw, vpw_bf, a_inw, ainw_bf, a_outw, aoutw_bf, ow, ow_bf, vpf,
      (float*)(ws + o_flags), (float*)ringA, (float*)ringB, (float*)ringX);
  // 2. fused weight permutes (whh x4 | wih x4 | bias x4)
  prep_weights<<<dim3(G4_, 9), dim3(64), 0, stream>>>(
      whh[0], (ushort_t*)(ws + o_whhp_hi[0]), (ushort_t*)(ws + o_whhp_lo[0]), whh[1],
      (ushort_t*)(ws + o_whhp_hi[1]), (ushort_t*)(ws + o_whhp_lo[1]), whh[2],
      (ushort_t*)(ws + o_whhp_hi[2]), (ushort_t*)(ws + o_whhp_lo[2]), whh[3],
      (ushort_t*)(ws + o_whhp_hi[3]), (ushort_t*)(ws + o_whhp_lo[3]),
      wih[0], (ushort_t*)(ws + o_wihp[0]), wih[1], (ushort_t*)(ws + o_wihp[1]),
      wih[2], (ushort_t*)(ws + o_wihp[2]), wih[3], (ushort_t*)(ws + o_wihp[3]),
      bih[0], bhh[0], (float*)(ws + o_bc[0]), bih[1], bhh[1], (float*)(ws + o_bc[1]),
      bih[2], bhh[2], (float*)(ws + o_bc[2]), bih[3], bhh[3], (float*)(ws + o_bc[3]));

  // 3-4. vproj: split-K x4 atomic fp32, then +vpb and cvt -> bf16
  gemm_nt_big_split<<<dim3(2, 80, 4), dim3(256), 0, stream>>>(video_bf, vpw_bf, vpf, B_ * TV_,
                                                              H_, VD_, VD_ / 4);
  bias_cvt_bf16<<<dim3((B_ * TV_ * H_ / 4 + 255) / 256), dim3(256), 0, stream>>>(
      vpf, vpb, vproj_bf, H_, B_ * TV_ * H_ / 4);

  // 5. encoder LSTM pair (A's x = vproj inline; no xg GEMM)
  lstm_ring<<<dim3(256), dim3(512), 0, stream>>>(
      vproj_bf, (const ushort_t*)(ws + o_wihp[0]), (const float*)(ws + o_bc[0]),
      (const ushort_t*)(ws + o_whhp_hi[0]), (const ushort_t*)(ws + o_whhp_lo[0]),
      (const ushort_t*)(ws + o_whhp_hi[1]), (const ushort_t*)(ws + o_whhp_lo[1]),
      (const ushort_t*)(ws + o_wihp[1]), (const float*)(ws + o_bc[1]), ringA, ringB, ringX,
      hse1, TV_, flagA0, flagB0);

  // 6. Q (inline embedding gather) + K + V in one dispatch
  gemm_qkv<<<dim3(8, 80, 3), dim3(256), 0, stream>>>(captions, emb_table, hse1, ainw_bf, a_inb,
                                                     Qf, Kf, Vf);

  // 7. MHA
  mha_kernel<<<dim3(4, B_), dim3(256), 0, stream>>>(Qf, Kf, Vf, attn_bf);

  // 8. attention out projection
  gemm_nt_mfma<ushort_t><<<dim3(8, TD_), dim3(256), 0, stream>>>(
      attn_bf, aoutw_bf, a_outb, nullptr, attd_bf, B_ * TD_, H_, H_);

  // 9. decoder LSTM pair (A's x = attd inline; no xg GEMM)
  lstm_ring<<<dim3(256), dim3(512), 0, stream>>>(
      attd_bf, (const ushort_t*)(ws + o_wihp[2]), (const float*)(ws + o_bc[2]),
      (const ushort_t*)(ws + o_whhp_hi[2]), (const ushort_t*)(ws + o_whhp_lo[2]),
      (const ushort_t*)(ws + o_whhp_hi[3]), (const ushort_t*)(ws + o_whhp_lo[3]),
      (const ushort_t*)(ws + o_wihp[3]), (const float*)(ws + o_bc[3]), ringA, ringB, ringX,
      hsd1, TD_, flagA1, flagB1);

  // 10. logits: (1216,512) x (10000,512)^T + ob
  gemm_nt_big<float><<<dim3((NV_ + 255) / 256, TD_), dim3(256), 0, stream>>>(
      hsd1, ow_bf, ob, nullptr, out, B_ * TD_, NV_, H_);
}